// Round 13
// baseline (9677.958 us; speedup 1.0000x reference)
//
#include <hip/hip_runtime.h>
#include <hip/hip_bf16.h>

// LatticeLSTM on MI355X — Round 13: 2 WGs/CU TLP latency hiding + early-issue.
// Measured base: R5 = 5607us (1.37us VALU + ~4.1us stall/step = h-trip + k0-pend
// residual, both LLC round trips). R7/R9 falsified all same-XCD L2 fast paths
// (stale data at L2 latency). R12 (8 seqs/WG on 64 CUs) was discarded by
// arithmetic: 4x per-CU compute = break-even best case.
// This round keeps R5's proven sc1 pub/poll protocol and phase structure,
// and attacks the stall three ways:
//   * 64 WGs/seq x 8 columns (512 WGs, 2 WGs/CU via __launch_bounds__(256,2)):
//     per-CU VALU load unchanged, but the CU's two WGs serve DIFFERENT seqs ->
//     one computes while the other spins (stall windows interleave).
//     Halved per-WG weight regs (~70 VGPR of weights vs ~140) helps occupancy.
//     No new deadlock mode: 512 WGs always fit at >=2 waves/SIMD.
//   * early-issue polls: pend loads issued before A1 matvecs, h loads issued
//     at top of B2 before staging+xw matvecs; gen-check after; spin on miss.
//   * publish cw0 (1-step-slack word) before cw1.
// Step layout (2 syncthreads/step, parity-double-buffered LDS):
//   P0 early pend loads | A1 matvecs(h(t-1),x) | A2 check/spin pend | S1
//   A3 alpha+gates, publish h | B2 early h loads + stage x(t+1) + xw matvecs
//   + check/spin h(t) | S2 | B3 word gates, publish pend (cw0 first)
// pmask data-independent: m0=(t>=1), m1=(t>=3); c_plain only at t=0.

#define Bq 8
#define Tq 1024
#define DCq 128
#define Hq 512
#define NWGY 64      // WGs per sequence
#define COLS 8       // H columns per WG
#define NTHR 256

typedef unsigned long long u64;

// ws byte offsets
#define HPUB_OFF 0u         // u64 h_pub[8][2][512]    = 65536
#define PEND_OFF 65536u     // u64 pend[8][4][2][512]  = 262144
#define WIHT_OFF  657408u   // bf16 [1536][128]
#define WHHT_OFF  1050624u  // bf16 [1536][512]
#define AWIHT_OFF 2623488u  // bf16 [512][128]
#define AWHHT_OFF 2754560u  // bf16 [512][512]
#define WWIHT_OFF 3278848u  // bf16 [1536][128]
#define WWHHT_OFF 3672064u  // bf16 [1536][512]  (end 4915200)

__device__ __forceinline__ float bflo(unsigned u){ return __uint_as_float(u << 16); }
__device__ __forceinline__ float bfhi(unsigned u){ return __uint_as_float(u & 0xffff0000u); }
__device__ __forceinline__ float sigm(float x){ return 1.0f / (1.0f + __expf(-x)); }

__device__ __forceinline__ void fma4(float& acc, uint2 w, float4 v){
  acc = fmaf(bflo(w.x), v.x, acc);
  acc = fmaf(bfhi(w.x), v.y, acc);
  acc = fmaf(bflo(w.y), v.z, acc);
  acc = fmaf(bfhi(w.y), v.w, acc);
}

__device__ __forceinline__ float red32(float x){
  x += __shfl_xor(x, 16, 32);
  x += __shfl_xor(x, 8, 32);
  x += __shfl_xor(x, 4, 32);
  x += __shfl_xor(x, 2, 32);
  x += __shfl_xor(x, 1, 32);
  return x;
}

__device__ __forceinline__ u64 pack64(float v, unsigned gen){
  return ((u64)gen << 32) | (u64)__float_as_uint(v);
}
__device__ __forceinline__ void pub64(u64* p, u64 v){
  __hip_atomic_store(p, v, __ATOMIC_RELAXED, __HIP_MEMORY_SCOPE_AGENT);
}
__device__ __forceinline__ u64 ld64(const u64* p){
  return __hip_atomic_load(p, __ATOMIC_RELAXED, __HIP_MEMORY_SCOPE_AGENT);
}
__device__ __forceinline__ unsigned genof(u64 v){ return (unsigned)(v >> 32); }
__device__ __forceinline__ float valof(u64 v){ return __uint_as_float((unsigned)v); }

// src [K][N] fp32 -> dst [N][K] bf16 (transpose + convert). K is pow2.
__global__ void transpose_bf16(const float* __restrict__ src, __hip_bfloat16* __restrict__ dst,
                               int kshift, int total, int N){
  const int K = 1 << kshift;
  for (int idx = blockIdx.x * blockDim.x + threadIdx.x; idx < total;
       idx += gridDim.x * blockDim.x){
    int n = idx >> kshift;
    int k = idx & (K - 1);
    dst[idx] = __float2bfloat16(src[(size_t)k * N + n]);
  }
}

__global__ void __launch_bounds__(NTHR, 2)
lattice_main(const float* __restrict__ char_emb,
             const int*   __restrict__ word_ids,
             const float* __restrict__ sense_table,
             const float* __restrict__ bias_b,
             const float* __restrict__ bias_ab,
             const float* __restrict__ bias_wb,
             unsigned char* __restrict__ ws,
             float* __restrict__ out)
{
  const int seq  = blockIdx.x;
  const int wg   = blockIdx.y;
  const int tid  = threadIdx.x;
  const int grp  = tid >> 5;          // 0..7: column group (32 lanes each)
  const int lane = tid & 31;
  const int J    = wg * COLS + grp;   // owned H column
  const int i0   = tid * 2, i1 = tid * 2 + 1;   // poll cells

  u64* hpub = (u64*)(ws + HPUB_OFF) + (size_t)seq * 2 * Hq;      // [parity][col]
  u64* pnd  = (u64*)(ws + PEND_OFF) + (size_t)seq * 4 * 2 * Hq;  // [slot][k][col]

  // ---- hoist weights: row J; lane covers k = it*128 + lane*4 ----
  uint2 Rwhh_i[4], Rwhh_o[4], Rwhh_g[4], Rawhh[4];
  uint2 Rwwh_f[4], Rwwh_i[4], Rwwh_g[4];
  uint2 Rwih_i, Rwih_o, Rwih_g, Rawih, Rwwi_f, Rwwi_i, Rwwi_g;
  {
    const uint2* w_hhT  = (const uint2*)(ws + WHHT_OFF);
    const uint2* aw_hhT = (const uint2*)(ws + AWHHT_OFF);
    const uint2* ww_hhT = (const uint2*)(ws + WWHHT_OFF);
    const uint2* whh_i = w_hhT  + (size_t)(0*Hq + J) * 128;
    const uint2* whh_o = w_hhT  + (size_t)(1*Hq + J) * 128;
    const uint2* whh_g = w_hhT  + (size_t)(2*Hq + J) * 128;
    const uint2* awhh  = aw_hhT + (size_t)J * 128;
    const uint2* wwh_f = ww_hhT + (size_t)(0*Hq + J) * 128;
    const uint2* wwh_i = ww_hhT + (size_t)(1*Hq + J) * 128;
    const uint2* wwh_g = ww_hhT + (size_t)(2*Hq + J) * 128;
#pragma unroll
    for (int it = 0; it < 4; ++it){
      const int q = it * 32 + lane;
      Rwhh_i[it] = whh_i[q];  Rwhh_o[it] = whh_o[q];  Rwhh_g[it] = whh_g[q];
      Rawhh[it]  = awhh[q];
      Rwwh_f[it] = wwh_f[q];  Rwwh_i[it] = wwh_i[q];  Rwwh_g[it] = wwh_g[q];
    }
    const uint2* w_ihT  = (const uint2*)(ws + WIHT_OFF);
    const uint2* aw_ihT = (const uint2*)(ws + AWIHT_OFF);
    const uint2* ww_ihT = (const uint2*)(ws + WWIHT_OFF);
    Rwih_i = (w_ihT  + (size_t)(0*Hq + J) * 32)[lane];
    Rwih_o = (w_ihT  + (size_t)(1*Hq + J) * 32)[lane];
    Rwih_g = (w_ihT  + (size_t)(2*Hq + J) * 32)[lane];
    Rawih  = (aw_ihT + (size_t)J * 32)[lane];
    Rwwi_f = (ww_ihT + (size_t)(0*Hq + J) * 32)[lane];
    Rwwi_i = (ww_ihT + (size_t)(1*Hq + J) * 32)[lane];
    Rwwi_g = (ww_ihT + (size_t)(2*Hq + J) * 32)[lane];
  }

  const float b_i  = bias_b[J], b_o = bias_b[Hq + J], b_g = bias_b[2*Hq + J];
  const float ab_J = bias_ab[J];
  const float wb_f = bias_wb[J], wb_i = bias_wb[Hq + J], wb_g = bias_wb[2*Hq + J];

  float* out_h = out + (size_t)seq * Tq * Hq;            // hs block
  float* out_c = out + ((size_t)Bq + seq) * Tq * Hq;     // cs block

  __shared__ __align__(16) float shH[2][Hq];      // h by parity: shH[t&1] = h(t)
  __shared__ __align__(16) float sh_p0[Hq];
  __shared__ __align__(16) float sh_p1[Hq];
  __shared__ __align__(16) float shx[2][DCq];     // x(t) in shx[t&1]
  __shared__ __align__(16) float shxw0[2][DCq];   // xw(t) in shxw*[t&1]
  __shared__ __align__(16) float shxw1[2][DCq];

  // ---- pre-loop staging: zeros + x(0), xw(0) ----
  shH[0][i0] = 0.f; shH[0][i1] = 0.f;
  shH[1][i0] = 0.f; shH[1][i1] = 0.f;
  sh_p0[i0] = 0.f; sh_p0[i1] = 0.f;
  sh_p1[i0] = 0.f; sh_p1[i1] = 0.f;
  if (tid < DCq){
    shx[0][tid] = char_emb[((size_t)seq * Tq + 0) * DCq + tid];
  } else {
    const int k = tid - DCq;
    const int w0 = word_ids[(size_t)seq * Tq * 2 + 0];
    const int w1 = word_ids[(size_t)seq * Tq * 2 + 1];
    shxw0[0][k] = sense_table[(size_t)w0 * DCq + k];
    shxw1[0][k] = sense_table[(size_t)w1 * DCq + k];
  }
  __syncthreads();

  for (int t = 0; t < Tq; ++t){
    const int par = t & 1;
    const float* hprev = shH[par ^ 1];     // h(t-1)

    // ---- P0: early-issue pend loads (sc1) — wait sinks under A1 ----
    const u64* p0 = pnd + ((size_t)(t & 3) * 2 + 0) * Hq;
    const u64* p1 = pnd + ((size_t)(t & 3) * 2 + 1) * Hq;
    u64 ea = 0, eb = 0, ec = 0, ed = 0;
    if (t >= 3){
      ea = ld64(p0 + i0); eb = ld64(p0 + i1);
      ec = ld64(p1 + i0); ed = ld64(p1 + i1);
    } else if (t >= 1){
      ea = ld64(p0 + i0); eb = ld64(p0 + i1);
    }

    // ---- A1: i/o/g/xa matvecs (pend NOT needed) ----
    float a_i = 0.f, a_o = 0.f, a_g = 0.f, a_xa = 0.f;
#pragma unroll
    for (int it = 0; it < 4; ++it){
      const int k0 = it * 128 + lane * 4;
      float4 hv = *(const float4*)(hprev + k0);
      fma4(a_i, Rwhh_i[it], hv);
      fma4(a_o, Rwhh_o[it], hv);
      fma4(a_g, Rwhh_g[it], hv);
    }
    {
      const int k0 = lane * 4;
      float4 xv = *(const float4*)(shx[par] + k0);
      fma4(a_i,  Rwih_i, xv);
      fma4(a_o,  Rwih_o, xv);
      fma4(a_g,  Rwih_g, xv);
      fma4(a_xa, Rawih,  xv);
    }

    // ---- A2: check early pend loads; spin only on miss ----
    if (t >= 3){
      const unsigned tg0 = (unsigned)t, tg1 = (unsigned)(t - 2);
      if (!(genof(ea) >= tg0 && genof(eb) >= tg0 &&
            genof(ec) >= tg1 && genof(ed) >= tg1)){
        for (;;){
          ea = ld64(p0 + i0); eb = ld64(p0 + i1);
          ec = ld64(p1 + i0); ed = ld64(p1 + i1);
          if (genof(ea) >= tg0 && genof(eb) >= tg0 &&
              genof(ec) >= tg1 && genof(ed) >= tg1) break;
        }
      }
      sh_p0[i0] = valof(ea); sh_p0[i1] = valof(eb);
      sh_p1[i0] = valof(ec); sh_p1[i1] = valof(ed);
    } else if (t >= 1){
      const unsigned tg0 = (unsigned)t;
      if (!(genof(ea) >= tg0 && genof(eb) >= tg0)){
        for (;;){
          ea = ld64(p0 + i0); eb = ld64(p0 + i1);
          if (genof(ea) >= tg0 && genof(eb) >= tg0) break;
        }
      }
      sh_p0[i0] = valof(ea); sh_p0[i1] = valof(eb);
      // sh_p1 stays zero (mask m1=0 for t<3)
    }
    __syncthreads();   // S1

    // ---- A3: alpha matvecs + gates + publish h ----
    float a_p0 = 0.f, a_p1 = 0.f;
#pragma unroll
    for (int it = 0; it < 4; ++it){
      const int k0 = it * 128 + lane * 4;
      float4 p0v = *(const float4*)(sh_p0 + k0);
      float4 p1v = *(const float4*)(sh_p1 + k0);
      fma4(a_p0, Rawhh[it], p0v);
      fma4(a_p1, Rawhh[it], p1v);
    }
    a_i  = red32(a_i);  a_o  = red32(a_o);  a_g  = red32(a_g);
    a_xa = red32(a_xa); a_p0 = red32(a_p0); a_p1 = red32(a_p1);

    const float gi = sigm(a_i + b_i);
    const float go = sigm(a_o + b_o);
    const float gg = tanhf(a_g + b_g);
    float c1;
    if (t == 0){
      c1 = gi * gg;                       // c_plain with c=0
    } else {
      const float base = a_xa + ab_J;
      const float ea0 = __expf(sigm(base + a_p0));   // m0=1 for t>=1
      const float ei  = __expf(gi);
      float num = ei * gg + ea0 * sh_p0[J];
      float den = ei + ea0;
      if (t >= 3){                                    // m1=1 for t>=3
        const float ea1 = __expf(sigm(base + a_p1));
        num += ea1 * sh_p1[J];
        den += ea1;
      }
      c1 = num / den;
    }
    const float h1 = go * tanhf(c1);
    if (lane == 0){
      pub64(hpub + (size_t)par * Hq + J, pack64(h1, (unsigned)(t + 1)));
      out_h[(size_t)t * Hq + J] = h1;
      out_c[(size_t)t * Hq + J] = c1;
    }

    // ---- B2: early h loads + stage x/xw(t+1) + xw matvecs + check h ----
    float x_f0 = 0.f, x_i0 = 0.f, x_g0 = 0.f, x_f1 = 0.f, x_i1 = 0.f, x_g1 = 0.f;
    {
      const u64* hp = hpub + (size_t)par * Hq;
      const unsigned tg = (unsigned)(t + 1);
      u64 ha = ld64(hp + i0), hb = ld64(hp + i1);   // early issue

      const int tn = (t + 1 < Tq) ? t + 1 : t;
      if (tid < DCq){
        shx[par ^ 1][tid] = char_emb[((size_t)seq * Tq + tn) * DCq + tid];
      } else {
        const int k = tid - DCq;
        const int w0 = word_ids[((size_t)seq * Tq + tn) * 2 + 0];
        const int w1 = word_ids[((size_t)seq * Tq + tn) * 2 + 1];
        shxw0[par ^ 1][k] = sense_table[(size_t)w0 * DCq + k];
        shxw1[par ^ 1][k] = sense_table[(size_t)w1 * DCq + k];
      }
      // h-independent parts of the word gates (reads shxw*[par], staged t-1)
      {
        const int k0 = lane * 4;
        float4 x0 = *(const float4*)(shxw0[par] + k0);
        float4 x1 = *(const float4*)(shxw1[par] + k0);
        fma4(x_f0, Rwwi_f, x0);  fma4(x_f1, Rwwi_f, x1);
        fma4(x_i0, Rwwi_i, x0);  fma4(x_i1, Rwwi_i, x1);
        fma4(x_g0, Rwwi_g, x0);  fma4(x_g1, Rwwi_g, x1);
      }
      x_f0 = red32(x_f0); x_i0 = red32(x_i0); x_g0 = red32(x_g0);
      x_f1 = red32(x_f1); x_i1 = red32(x_i1); x_g1 = red32(x_g1);

      // check h(t) — the ONE exposed round trip; spin only on miss
      if (!(genof(ha) >= tg && genof(hb) >= tg)){
        for (;;){
          ha = ld64(hp + i0); hb = ld64(hp + i1);
          if (genof(ha) >= tg && genof(hb) >= tg) break;
        }
      }
      shH[par][i0] = valof(ha); shH[par][i1] = valof(hb);
    }
    __syncthreads();   // S2

    // ---- B3: h-dependent word gates + publish pend (cw0 first) ----
    float r_f = 0.f, r_i = 0.f, r_g = 0.f;
#pragma unroll
    for (int it = 0; it < 4; ++it){
      const int k0 = it * 128 + lane * 4;
      float4 hv = *(const float4*)(shH[par] + k0);
      fma4(r_f, Rwwh_f[it], hv);
      fma4(r_i, Rwwh_i[it], hv);
      fma4(r_g, Rwwh_g[it], hv);
    }
    r_f = red32(r_f);  r_i = red32(r_i);  r_g = red32(r_g);

    if (lane == 0){
      const float f0  = sigm(r_f + x_f0 + wb_f);
      const float iw0 = sigm(r_i + x_i0 + wb_i);
      const float g0  = tanhf(r_g + x_g0 + wb_g);
      const float cw0 = f0 * c1 + iw0 * g0;
      // cw0 (len-2 word, consumed at t+1: 1-step slack) published FIRST
      pub64(pnd + ((size_t)((t + 1) & 3) * 2 + 0) * Hq + J,
            pack64(cw0, (unsigned)(t + 1)));
      const float f1  = sigm(r_f + x_f1 + wb_f);
      const float iw1 = sigm(r_i + x_i1 + wb_i);
      const float g1  = tanhf(r_g + x_g1 + wb_g);
      const float cw1 = f1 * c1 + iw1 * g1;
      pub64(pnd + ((size_t)((t + 3) & 3) * 2 + 1) * Hq + J,
            pack64(cw1, (unsigned)(t + 1)));
    }
    // no barrier: next A1 reads shH[par]/shx[par^1] written before S2; next A2
    // re-writes sh_p0/p1 whose last read (A3) is separated by S2.
  }
}

extern "C" void kernel_launch(void* const* d_in, const int* in_sizes, int n_in,
                              void* d_out, int out_size, void* d_ws, size_t ws_size,
                              hipStream_t stream){
  const float* char_emb = (const float*)d_in[0];
  const int*   word_ids = (const int*)d_in[1];
  const float* sense    = (const float*)d_in[2];
  const float* w_ih     = (const float*)d_in[3];
  const float* w_hh     = (const float*)d_in[4];
  const float* bb       = (const float*)d_in[5];
  const float* aw_ih    = (const float*)d_in[6];
  const float* aw_hh    = (const float*)d_in[7];
  const float* ab       = (const float*)d_in[8];
  const float* ww_ih    = (const float*)d_in[9];
  const float* ww_hh    = (const float*)d_in[10];
  const float* wb       = (const float*)d_in[11];
  unsigned char* ws = (unsigned char*)d_ws;
  float* out = (float*)d_out;

  // zero all generation words (h_pub + pend)
  hipMemsetAsync(ws, 0, WIHT_OFF, stream);

  // one-time (per launch) weight convert+transpose to bf16
  transpose_bf16<<<512, NTHR, 0, stream>>>(w_ih,  (__hip_bfloat16*)(ws + WIHT_OFF),  7, 128*1536, 1536);
  transpose_bf16<<<512, NTHR, 0, stream>>>(w_hh,  (__hip_bfloat16*)(ws + WHHT_OFF),  9, 512*1536, 1536);
  transpose_bf16<<<512, NTHR, 0, stream>>>(aw_ih, (__hip_bfloat16*)(ws + AWIHT_OFF), 7, 128*512,  512);
  transpose_bf16<<<512, NTHR, 0, stream>>>(aw_hh, (__hip_bfloat16*)(ws + AWHHT_OFF), 9, 512*512,  512);
  transpose_bf16<<<512, NTHR, 0, stream>>>(ww_ih, (__hip_bfloat16*)(ws + WWIHT_OFF), 7, 128*1536, 1536);
  transpose_bf16<<<512, NTHR, 0, stream>>>(ww_hh, (__hip_bfloat16*)(ws + WWHHT_OFF), 9, 512*1536, 1536);

  dim3 grid(Bq, NWGY);   // x = seq, y = wg slice (512 WGs, 2 per CU)
  lattice_main<<<grid, NTHR, 0, stream>>>(char_emb, word_ids, sense, bb, ab, wb, ws, out);
}

// Round 15
// 6717.456 us; speedup vs baseline: 1.4407x; 1.4407x over previous
//
#include <hip/hip_runtime.h>
#include <hip/hip_bf16.h>

// LatticeLSTM on MI355X — Round 14 (resubmit; R14 bench was an acquisition
// timeout): R5 (measured 5607us, best) + minimal deltas.
// Evidence so far: R7/R9 falsified same-XCD L2 fast paths (stale at L2 latency);
// R13 falsified 2-WG/CU TLP hiding (lockstep seqs stall together; 9678us).
// Model: per step = 1.37us VALU + ~4.1us on TWO serial LLC round trips
// (h: A3->B3, pend: B3->A3(t+1); serial on the recurrence h->cw0->c1).
// R14 keeps R5's exact topology/protocol (8x32 WGs, 256thr, 16 cols/WG,
// 1 WG/CU, sc1 pack64 gen-protocol) and adds ONLY:
//   1. early-issue pend loads BEFORE A1 (catch-RT sinks under matvecs);
//      gen-check after, spin only on miss.
//   2. early-issue h loads at top of B2, before staging + xw matvecs.
//   3. cw0 (1-step-slack word) published before cw1.
// Step layout (2 syncthreads/step, parity-double-buffered LDS):
//   P0 early pend loads | A1 matvecs(h(t-1),x) | A2 check/spin pend | S1
//   A3 alpha+gates, publish h | B2 early h loads + stage x(t+1) + xw matvecs
//   + check/spin h(t) | S2 | B3 word gates, publish pend (cw0 first)
// pmask is data-independent: m0=(t>=1), m1=(t>=3); c_plain only at t=0.
// Progress needs all 256 WGs co-resident (1 WG/CU; LDS ~11KB, VGPR<256).

#define Bq 8
#define Tq 1024
#define DCq 128
#define Hq 512
#define NWG 32
#define NTHR 256

typedef unsigned long long u64;

// ws byte offsets
#define HPUB_OFF  0u         // u64 h_pub[8][2][512]     = 65536
#define PEND_OFF  65536u     // u64 pend[8][4][2][512]   = 262144
#define WIHT_OFF  327680u    // bf16 [1536][128]
#define WHHT_OFF  720896u    // bf16 [1536][512]
#define AWIHT_OFF 2293760u   // bf16 [512][128]
#define AWHHT_OFF 2424832u   // bf16 [512][512]
#define WWIHT_OFF 2949120u   // bf16 [1536][128]
#define WWHHT_OFF 3342336u   // bf16 [1536][512]  (end 4915200)

__device__ __forceinline__ float bflo(unsigned u){ return __uint_as_float(u << 16); }
__device__ __forceinline__ float bfhi(unsigned u){ return __uint_as_float(u & 0xffff0000u); }
__device__ __forceinline__ float sigm(float x){ return 1.0f / (1.0f + __expf(-x)); }

__device__ __forceinline__ void fma4(float& acc, uint2 w, float4 v){
  acc = fmaf(bflo(w.x), v.x, acc);
  acc = fmaf(bfhi(w.x), v.y, acc);
  acc = fmaf(bflo(w.y), v.z, acc);
  acc = fmaf(bfhi(w.y), v.w, acc);
}

__device__ __forceinline__ float red16(float x){
  x += __shfl_xor(x, 8, 16);
  x += __shfl_xor(x, 4, 16);
  x += __shfl_xor(x, 2, 16);
  x += __shfl_xor(x, 1, 16);
  return x;
}

__device__ __forceinline__ u64 pack64(float v, unsigned gen){
  return ((u64)gen << 32) | (u64)__float_as_uint(v);
}
__device__ __forceinline__ void pub64(u64* p, u64 v){
  __hip_atomic_store(p, v, __ATOMIC_RELAXED, __HIP_MEMORY_SCOPE_AGENT);
}
__device__ __forceinline__ u64 ld64(const u64* p){
  return __hip_atomic_load(p, __ATOMIC_RELAXED, __HIP_MEMORY_SCOPE_AGENT);
}
__device__ __forceinline__ unsigned genof(u64 v){ return (unsigned)(v >> 32); }
__device__ __forceinline__ float valof(u64 v){ return __uint_as_float((unsigned)v); }

// src [K][N] fp32 -> dst [N][K] bf16 (transpose + convert). K is pow2.
__global__ void transpose_bf16(const float* __restrict__ src, __hip_bfloat16* __restrict__ dst,
                               int kshift, int total, int N){
  const int K = 1 << kshift;
  for (int idx = blockIdx.x * blockDim.x + threadIdx.x; idx < total;
       idx += gridDim.x * blockDim.x){
    int n = idx >> kshift;
    int k = idx & (K - 1);
    dst[idx] = __float2bfloat16(src[(size_t)k * N + n]);
  }
}

__global__ void __launch_bounds__(NTHR, 1)
lattice_main(const float* __restrict__ char_emb,
             const int*   __restrict__ word_ids,
             const float* __restrict__ sense_table,
             const float* __restrict__ bias_b,
             const float* __restrict__ bias_ab,
             const float* __restrict__ bias_wb,
             unsigned char* __restrict__ ws,
             float* __restrict__ out)
{
  const int seq  = blockIdx.x;
  const int wg   = blockIdx.y;
  const int tid  = threadIdx.x;
  const int grp  = tid >> 4;
  const int lane = tid & 15;
  const int J    = wg * 16 + grp;               // owned H column
  const int i0   = tid * 2, i1 = tid * 2 + 1;   // poll columns for this thread

  u64* hpub = (u64*)(ws + HPUB_OFF)  + (size_t)seq * 2 * Hq;      // [parity][col]
  u64* pnd  = (u64*)(ws + PEND_OFF) + (size_t)seq * 4 * 2 * Hq;   // [slot][k][col]

  const uint2* w_ihT  = (const uint2*)(ws + WIHT_OFF);
  const uint2* w_hhT  = (const uint2*)(ws + WHHT_OFF);
  const uint2* aw_ihT = (const uint2*)(ws + AWIHT_OFF);
  const uint2* aw_hhT = (const uint2*)(ws + AWHHT_OFF);
  const uint2* ww_ihT = (const uint2*)(ws + WWIHT_OFF);
  const uint2* ww_hhT = (const uint2*)(ws + WWHHT_OFF);

  // ---- hoist ALL weights into registers (addresses are t-invariant) ----
  uint2 Rwhh_i[8], Rwhh_o[8], Rwhh_g[8], Rawhh[8];
  uint2 Rwwh_f[8], Rwwh_i[8], Rwwh_g[8];
  uint2 Rwih_i[2], Rwih_o[2], Rwih_g[2], Rawih[2];
  uint2 Rwwi_f[2], Rwwi_i[2], Rwwi_g[2];
  {
    const uint2* whh_i = w_hhT  + (size_t)(0*Hq + J) * 128;
    const uint2* whh_o = w_hhT  + (size_t)(1*Hq + J) * 128;
    const uint2* whh_g = w_hhT  + (size_t)(2*Hq + J) * 128;
    const uint2* awhh  = aw_hhT + (size_t)J * 128;
    const uint2* wwh_f = ww_hhT + (size_t)(0*Hq + J) * 128;
    const uint2* wwh_i = ww_hhT + (size_t)(1*Hq + J) * 128;
    const uint2* wwh_g = ww_hhT + (size_t)(2*Hq + J) * 128;
#pragma unroll
    for (int it = 0; it < 8; ++it){
      const int q = it * 16 + lane;
      Rwhh_i[it] = whh_i[q];  Rwhh_o[it] = whh_o[q];  Rwhh_g[it] = whh_g[q];
      Rawhh[it]  = awhh[q];
      Rwwh_f[it] = wwh_f[q];  Rwwh_i[it] = wwh_i[q];  Rwwh_g[it] = wwh_g[q];
    }
    const uint2* wih_i = w_ihT  + (size_t)(0*Hq + J) * 32;
    const uint2* wih_o = w_ihT  + (size_t)(1*Hq + J) * 32;
    const uint2* wih_g = w_ihT  + (size_t)(2*Hq + J) * 32;
    const uint2* awih  = aw_ihT + (size_t)J * 32;
    const uint2* wwi_f = ww_ihT + (size_t)(0*Hq + J) * 32;
    const uint2* wwi_i = ww_ihT + (size_t)(1*Hq + J) * 32;
    const uint2* wwi_g = ww_ihT + (size_t)(2*Hq + J) * 32;
#pragma unroll
    for (int it = 0; it < 2; ++it){
      const int q = it * 16 + lane;
      Rwih_i[it] = wih_i[q];  Rwih_o[it] = wih_o[q];  Rwih_g[it] = wih_g[q];
      Rawih[it]  = awih[q];
      Rwwi_f[it] = wwi_f[q];  Rwwi_i[it] = wwi_i[q];  Rwwi_g[it] = wwi_g[q];
    }
  }

  const float b_i  = bias_b[J], b_o = bias_b[Hq + J], b_g = bias_b[2*Hq + J];
  const float ab_J = bias_ab[J];
  const float wb_f = bias_wb[J], wb_i = bias_wb[Hq + J], wb_g = bias_wb[2*Hq + J];

  float* out_h = out + (size_t)seq * Tq * Hq;            // hs block
  float* out_c = out + ((size_t)Bq + seq) * Tq * Hq;     // cs block

  __shared__ __align__(16) float shH[2][Hq];      // h by parity: shH[t&1] = h(t)
  __shared__ __align__(16) float sh_p0[Hq];
  __shared__ __align__(16) float sh_p1[Hq];
  __shared__ __align__(16) float shx[2][DCq];     // x(t) in shx[t&1]
  __shared__ __align__(16) float shxw0[2][DCq];   // xw(t) in shxw*[t&1]
  __shared__ __align__(16) float shxw1[2][DCq];

  // ---- pre-loop staging: zeros + x(0), xw(0) ----
  shH[0][i0] = 0.f; shH[0][i1] = 0.f;
  shH[1][i0] = 0.f; shH[1][i1] = 0.f;
  sh_p0[i0] = 0.f; sh_p0[i1] = 0.f;
  sh_p1[i0] = 0.f; sh_p1[i1] = 0.f;
  if (tid < DCq){
    shx[0][tid] = char_emb[((size_t)seq * Tq + 0) * DCq + tid];
  } else {
    const int k = tid - DCq;
    const int w0 = word_ids[(size_t)seq * Tq * 2 + 0];
    const int w1 = word_ids[(size_t)seq * Tq * 2 + 1];
    shxw0[0][k] = sense_table[(size_t)w0 * DCq + k];
    shxw1[0][k] = sense_table[(size_t)w1 * DCq + k];
  }
  __syncthreads();

  for (int t = 0; t < Tq; ++t){
    const int par = t & 1;
    const float* hprev = shH[par ^ 1];     // h(t-1)

    // ---- P0: early-issue pend loads — catch-RT sinks under A1 ----
    const u64* p0 = pnd + ((size_t)(t & 3) * 2 + 0) * Hq;
    const u64* p1 = pnd + ((size_t)(t & 3) * 2 + 1) * Hq;
    u64 ea = 0, eb = 0, ec = 0, ed = 0;
    if (t >= 3){
      ea = ld64(p0 + i0); eb = ld64(p0 + i1);
      ec = ld64(p1 + i0); ed = ld64(p1 + i1);
    } else if (t >= 1){
      ea = ld64(p0 + i0); eb = ld64(p0 + i1);
    }

    // ---- A1: i/o/g/xa matvecs (pend NOT needed) ----
    float a_i = 0.f, a_o = 0.f, a_g = 0.f, a_xa = 0.f;
#pragma unroll
    for (int it = 0; it < 8; ++it){
      const int k0 = it * 64 + lane * 4;
      float4 hv = *(const float4*)(hprev + k0);
      fma4(a_i, Rwhh_i[it], hv);
      fma4(a_o, Rwhh_o[it], hv);
      fma4(a_g, Rwhh_g[it], hv);
    }
#pragma unroll
    for (int it = 0; it < 2; ++it){
      const int k0 = it * 64 + lane * 4;
      float4 xv = *(const float4*)(shx[par] + k0);
      fma4(a_i,  Rwih_i[it], xv);
      fma4(a_o,  Rwih_o[it], xv);
      fma4(a_g,  Rwih_g[it], xv);
      fma4(a_xa, Rawih[it],  xv);
    }

    // ---- A2: check early pend loads; spin only on miss ----
    if (t >= 3){
      const unsigned tg0 = (unsigned)t, tg1 = (unsigned)(t - 2);
      if (!(genof(ea) >= tg0 && genof(eb) >= tg0 &&
            genof(ec) >= tg1 && genof(ed) >= tg1)){
        for (;;){
          ea = ld64(p0 + i0); eb = ld64(p0 + i1);
          ec = ld64(p1 + i0); ed = ld64(p1 + i1);
          if (genof(ea) >= tg0 && genof(eb) >= tg0 &&
              genof(ec) >= tg1 && genof(ed) >= tg1) break;
        }
      }
      sh_p0[i0] = valof(ea); sh_p0[i1] = valof(eb);
      sh_p1[i0] = valof(ec); sh_p1[i1] = valof(ed);
    } else if (t >= 1){
      const unsigned tg0 = (unsigned)t;
      if (!(genof(ea) >= tg0 && genof(eb) >= tg0)){
        for (;;){
          ea = ld64(p0 + i0); eb = ld64(p0 + i1);
          if (genof(ea) >= tg0 && genof(eb) >= tg0) break;
        }
      }
      sh_p0[i0] = valof(ea); sh_p0[i1] = valof(eb);
      // sh_p1 stays zero (mask m1=0 for t<3)
    }
    __syncthreads();   // S1

    // ---- A3: alpha matvecs + gates ----
    float a_p0 = 0.f, a_p1 = 0.f;
#pragma unroll
    for (int it = 0; it < 8; ++it){
      const int k0 = it * 64 + lane * 4;
      float4 p0v = *(const float4*)(sh_p0 + k0);
      float4 p1v = *(const float4*)(sh_p1 + k0);
      fma4(a_p0, Rawhh[it], p0v);
      fma4(a_p1, Rawhh[it], p1v);
    }
    a_i  = red16(a_i);  a_o  = red16(a_o);  a_g  = red16(a_g);
    a_xa = red16(a_xa); a_p0 = red16(a_p0); a_p1 = red16(a_p1);

    const float gi = sigm(a_i + b_i);
    const float go = sigm(a_o + b_o);
    const float gg = tanhf(a_g + b_g);
    float c1;
    if (t == 0){
      c1 = gi * gg;                       // c_plain with c=0
    } else {
      const float base = a_xa + ab_J;
      const float ea0 = __expf(sigm(base + a_p0));   // m0=1 for t>=1
      const float ei  = __expf(gi);
      float num = ei * gg + ea0 * sh_p0[J];
      float den = ei + ea0;
      if (t >= 3){                                    // m1=1 for t>=3
        const float ea1 = __expf(sigm(base + a_p1));
        num += ea1 * sh_p1[J];
        den += ea1;
      }
      c1 = num / den;
    }
    const float h1 = go * tanhf(c1);
    if (lane == 0){
      pub64(hpub + (size_t)par * Hq + J, pack64(h1, (unsigned)(t + 1)));
      out_h[(size_t)t * Hq + J] = h1;
      out_c[(size_t)t * Hq + J] = c1;
    }

    // ---- B2: early h loads + stage x/xw(t+1) + xw matvecs + check h ----
    float x_f0 = 0.f, x_i0 = 0.f, x_g0 = 0.f, x_f1 = 0.f, x_i1 = 0.f, x_g1 = 0.f;
    {
      const u64* hp = hpub + (size_t)par * Hq;
      const unsigned tg = (unsigned)(t + 1);
      u64 ha = ld64(hp + i0), hb = ld64(hp + i1);   // early issue

      const int tn = (t + 1 < Tq) ? t + 1 : t;
      if (tid < DCq){
        shx[par ^ 1][tid] = char_emb[((size_t)seq * Tq + tn) * DCq + tid];
      } else {
        const int k = tid - DCq;
        const int w0 = word_ids[((size_t)seq * Tq + tn) * 2 + 0];
        const int w1 = word_ids[((size_t)seq * Tq + tn) * 2 + 1];
        shxw0[par ^ 1][k] = sense_table[(size_t)w0 * DCq + k];
        shxw1[par ^ 1][k] = sense_table[(size_t)w1 * DCq + k];
      }
      // h-independent parts of the word gates (reads shxw*[par], staged at t-1)
#pragma unroll
      for (int it = 0; it < 2; ++it){
        const int k0 = it * 64 + lane * 4;
        float4 x0 = *(const float4*)(shxw0[par] + k0);
        float4 x1 = *(const float4*)(shxw1[par] + k0);
        fma4(x_f0, Rwwi_f[it], x0);  fma4(x_f1, Rwwi_f[it], x1);
        fma4(x_i0, Rwwi_i[it], x0);  fma4(x_i1, Rwwi_i[it], x1);
        fma4(x_g0, Rwwi_g[it], x0);  fma4(x_g1, Rwwi_g[it], x1);
      }
      x_f0 = red16(x_f0); x_i0 = red16(x_i0); x_g0 = red16(x_g0);
      x_f1 = red16(x_f1); x_i1 = red16(x_i1); x_g1 = red16(x_g1);

      // check h(t) — the ONE exposed round trip; spin only on miss
      if (!(genof(ha) >= tg && genof(hb) >= tg)){
        for (;;){
          ha = ld64(hp + i0); hb = ld64(hp + i1);
          if (genof(ha) >= tg && genof(hb) >= tg) break;
        }
      }
      shH[par][i0] = valof(ha); shH[par][i1] = valof(hb);
    }
    __syncthreads();   // S2

    // ---- B3: h-dependent word gates + publish pend (cw0 first) ----
    float r_f = 0.f, r_i = 0.f, r_g = 0.f;
#pragma unroll
    for (int it = 0; it < 8; ++it){
      const int k0 = it * 64 + lane * 4;
      float4 hv = *(const float4*)(shH[par] + k0);
      fma4(r_f, Rwwh_f[it], hv);
      fma4(r_i, Rwwh_i[it], hv);
      fma4(r_g, Rwwh_g[it], hv);
    }
    r_f = red16(r_f);  r_i = red16(r_i);  r_g = red16(r_g);

    if (lane == 0){
      const float f0  = sigm(r_f + x_f0 + wb_f);
      const float iw0 = sigm(r_i + x_i0 + wb_i);
      const float g0  = tanhf(r_g + x_g0 + wb_g);
      const float cw0 = f0 * c1 + iw0 * g0;
      // cw0 (len-2 word, consumed at t+1: 1-step slack) published FIRST
      pub64(pnd + ((size_t)((t + 1) & 3) * 2 + 0) * Hq + J,
            pack64(cw0, (unsigned)(t + 1)));
      const float f1  = sigm(r_f + x_f1 + wb_f);
      const float iw1 = sigm(r_i + x_i1 + wb_i);
      const float g1  = tanhf(r_g + x_g1 + wb_g);
      const float cw1 = f1 * c1 + iw1 * g1;
      pub64(pnd + ((size_t)((t + 3) & 3) * 2 + 1) * Hq + J,
            pack64(cw1, (unsigned)(t + 1)));
    }
    // no barrier here: next A1 touches only shH[par^1]/shx[par^1] (disjoint),
    // next A2 LDS writes are fenced by S1; pend LDS buffers re-written only
    // after S2 of this step (cross-thread ordering via S1/S2 chain).
  }
}

extern "C" void kernel_launch(void* const* d_in, const int* in_sizes, int n_in,
                              void* d_out, int out_size, void* d_ws, size_t ws_size,
                              hipStream_t stream){
  const float* char_emb = (const float*)d_in[0];
  const int*   word_ids = (const int*)d_in[1];
  const float* sense    = (const float*)d_in[2];
  const float* w_ih     = (const float*)d_in[3];
  const float* w_hh     = (const float*)d_in[4];
  const float* bb       = (const float*)d_in[5];
  const float* aw_ih    = (const float*)d_in[6];
  const float* aw_hh    = (const float*)d_in[7];
  const float* ab       = (const float*)d_in[8];
  const float* ww_ih    = (const float*)d_in[9];
  const float* ww_hh    = (const float*)d_in[10];
  const float* wb       = (const float*)d_in[11];
  unsigned char* ws = (unsigned char*)d_ws;
  float* out = (float*)d_out;

  // zero all generation words (h_pub + pend) — ws is re-poisoned before every launch
  hipMemsetAsync(ws, 0, WIHT_OFF, stream);

  // one-time (per launch) weight convert+transpose to bf16
  transpose_bf16<<<512, NTHR, 0, stream>>>(w_ih,  (__hip_bfloat16*)(ws + WIHT_OFF),  7, 128*1536, 1536);
  transpose_bf16<<<512, NTHR, 0, stream>>>(w_hh,  (__hip_bfloat16*)(ws + WHHT_OFF),  9, 512*1536, 1536);
  transpose_bf16<<<512, NTHR, 0, stream>>>(aw_ih, (__hip_bfloat16*)(ws + AWIHT_OFF), 7, 128*512,  512);
  transpose_bf16<<<512, NTHR, 0, stream>>>(aw_hh, (__hip_bfloat16*)(ws + AWHHT_OFF), 9, 512*512,  512);
  transpose_bf16<<<512, NTHR, 0, stream>>>(ww_ih, (__hip_bfloat16*)(ws + WWIHT_OFF), 7, 128*1536, 1536);
  transpose_bf16<<<512, NTHR, 0, stream>>>(ww_hh, (__hip_bfloat16*)(ws + WWHHT_OFF), 9, 512*1536, 1536);

  dim3 grid(Bq, NWG);   // x = seq, y = wg slice (256 WGs, 1 per CU)
  lattice_main<<<grid, NTHR, 0, stream>>>(char_emb, word_ids, sense, bb, ab, wb, ws, out);
}

// Round 16
// 5603.440 us; speedup vs baseline: 1.7271x; 1.1988x over previous
//
#include <hip/hip_runtime.h>
#include <hip/hip_bf16.h>

// LatticeLSTM on MI355X — Round 16: exact revert to R5 (measured 5606.9us best).
// Post-mortem ledger (all measured):
//   R5  = 5607us  <- this kernel
//   R7  = 18149us (sc0-store fast path: stale at L2 latency, 64-iter timeouts)
//   R9  = 8245us  (merged dual-scope polls: 2x poll bytes, no fewer iters)
//   R13 = 9678us  (2 WG/CU TLP: lockstep seqs stall together + 47ms outlier)
//   R14 = 6717us  (early-issue polls: always-miss -> +1 RT/poll, +35MB FETCH)
// Model (constrained by all six runs): per step = 1.37us VALU + two SERIAL
// LLC round trips (h: A3->B2, pend: B3->A2 of t+1; serial on the recurrence
// h->cw0->c1), ~2us each incl. 32-WG skew. R5's late-poll placement, publish
// ordering, and 8x32 topology are each validated as local optima by the
// failed variants. This is the structural floor for this dataflow.
// Step layout (2 syncthreads/step, parity-double-buffered LDS):
//   A1: i/o/g/xa matvecs over h(t-1),x(t)   [pend NOT needed]
//   A2: poll pend for step t (published last step -> usually visible)
//   S1
//   A3: alpha matvecs + gates -> c1,h1; publish {h1,gen} (8B atomic)
//   B2: stage x/xw(t+1) (overlaps) + poll full h(t)  <-- the ONE exposed trip
//   S2
//   B3: word gates -> cw0,cw1; publish pend {val,gen}
// All spin loops issue their 2-4 loads independently (one round trip, not
// serialized) and have NO s_sleep: the ~700cyc dependent-load latency is the
// backoff; addresses are distributed (no hot line).
// pmask is data-independent: m0=(t>=1), m1=(t>=3); c_plain only at t=0.
// Progress needs all 256 WGs co-resident (1 WG/CU; LDS ~11KB, VGPR<256).

#define Bq 8
#define Tq 1024
#define DCq 128
#define Hq 512
#define NWG 32
#define NTHR 256

typedef unsigned long long u64;

// ws byte offsets
#define HPUB_OFF  0u         // u64 h_pub[8][2][512]     = 65536
#define PENDP_OFF 65536u     // u64 pend[8][4][2][512]   = 262144
#define WIHT_OFF  327680u    // bf16 [1536][128]
#define WHHT_OFF  720896u    // bf16 [1536][512]
#define AWIHT_OFF 2293760u   // bf16 [512][128]
#define AWHHT_OFF 2424832u   // bf16 [512][512]
#define WWIHT_OFF 2949120u   // bf16 [1536][128]
#define WWHHT_OFF 3342336u   // bf16 [1536][512]  (end 4915200)

__device__ __forceinline__ float bflo(unsigned u){ return __uint_as_float(u << 16); }
__device__ __forceinline__ float bfhi(unsigned u){ return __uint_as_float(u & 0xffff0000u); }
__device__ __forceinline__ float sigm(float x){ return 1.0f / (1.0f + __expf(-x)); }

__device__ __forceinline__ void fma4(float& acc, uint2 w, float4 v){
  acc = fmaf(bflo(w.x), v.x, acc);
  acc = fmaf(bfhi(w.x), v.y, acc);
  acc = fmaf(bflo(w.y), v.z, acc);
  acc = fmaf(bfhi(w.y), v.w, acc);
}

__device__ __forceinline__ float red16(float x){
  x += __shfl_xor(x, 8, 16);
  x += __shfl_xor(x, 4, 16);
  x += __shfl_xor(x, 2, 16);
  x += __shfl_xor(x, 1, 16);
  return x;
}

__device__ __forceinline__ u64 pack64(float v, unsigned gen){
  return ((u64)gen << 32) | (u64)__float_as_uint(v);
}
__device__ __forceinline__ void pub64(u64* p, float v, unsigned gen){
  __hip_atomic_store(p, pack64(v, gen), __ATOMIC_RELAXED, __HIP_MEMORY_SCOPE_AGENT);
}
__device__ __forceinline__ u64 ld64(const u64* p){
  return __hip_atomic_load(p, __ATOMIC_RELAXED, __HIP_MEMORY_SCOPE_AGENT);
}
__device__ __forceinline__ unsigned genof(u64 v){ return (unsigned)(v >> 32); }
__device__ __forceinline__ float valof(u64 v){ return __uint_as_float((unsigned)v); }

// src [K][N] fp32 -> dst [N][K] bf16 (transpose + convert). K is pow2.
__global__ void transpose_bf16(const float* __restrict__ src, __hip_bfloat16* __restrict__ dst,
                               int kshift, int total, int N){
  const int K = 1 << kshift;
  for (int idx = blockIdx.x * blockDim.x + threadIdx.x; idx < total;
       idx += gridDim.x * blockDim.x){
    int n = idx >> kshift;
    int k = idx & (K - 1);
    dst[idx] = __float2bfloat16(src[(size_t)k * N + n]);
  }
}

__global__ void __launch_bounds__(NTHR, 1)
lattice_main(const float* __restrict__ char_emb,
             const int*   __restrict__ word_ids,
             const float* __restrict__ sense_table,
             const float* __restrict__ bias_b,
             const float* __restrict__ bias_ab,
             const float* __restrict__ bias_wb,
             unsigned char* __restrict__ ws,
             float* __restrict__ out)
{
  const int seq  = blockIdx.x;
  const int wg   = blockIdx.y;
  const int tid  = threadIdx.x;
  const int grp  = tid >> 4;
  const int lane = tid & 15;
  const int J    = wg * 16 + grp;               // owned H column
  const int i0   = tid * 2, i1 = tid * 2 + 1;   // poll columns for this thread

  u64* hpub = (u64*)(ws + HPUB_OFF)  + (size_t)seq * 2 * Hq;      // [parity][col]
  u64* pnd  = (u64*)(ws + PENDP_OFF) + (size_t)seq * 4 * 2 * Hq;  // [slot][k][col]

  const uint2* w_ihT  = (const uint2*)(ws + WIHT_OFF);
  const uint2* w_hhT  = (const uint2*)(ws + WHHT_OFF);
  const uint2* aw_ihT = (const uint2*)(ws + AWIHT_OFF);
  const uint2* aw_hhT = (const uint2*)(ws + AWHHT_OFF);
  const uint2* ww_ihT = (const uint2*)(ws + WWIHT_OFF);
  const uint2* ww_hhT = (const uint2*)(ws + WWHHT_OFF);

  // ---- hoist ALL weights into registers (addresses are t-invariant) ----
  uint2 Rwhh_i[8], Rwhh_o[8], Rwhh_g[8], Rawhh[8];
  uint2 Rwwh_f[8], Rwwh_i[8], Rwwh_g[8];
  uint2 Rwih_i[2], Rwih_o[2], Rwih_g[2], Rawih[2];
  uint2 Rwwi_f[2], Rwwi_i[2], Rwwi_g[2];
  {
    const uint2* whh_i = w_hhT  + (size_t)(0*Hq + J) * 128;
    const uint2* whh_o = w_hhT  + (size_t)(1*Hq + J) * 128;
    const uint2* whh_g = w_hhT  + (size_t)(2*Hq + J) * 128;
    const uint2* awhh  = aw_hhT + (size_t)J * 128;
    const uint2* wwh_f = ww_hhT + (size_t)(0*Hq + J) * 128;
    const uint2* wwh_i = ww_hhT + (size_t)(1*Hq + J) * 128;
    const uint2* wwh_g = ww_hhT + (size_t)(2*Hq + J) * 128;
#pragma unroll
    for (int it = 0; it < 8; ++it){
      const int q = it * 16 + lane;
      Rwhh_i[it] = whh_i[q];  Rwhh_o[it] = whh_o[q];  Rwhh_g[it] = whh_g[q];
      Rawhh[it]  = awhh[q];
      Rwwh_f[it] = wwh_f[q];  Rwwh_i[it] = wwh_i[q];  Rwwh_g[it] = wwh_g[q];
    }
    const uint2* wih_i = w_ihT  + (size_t)(0*Hq + J) * 32;
    const uint2* wih_o = w_ihT  + (size_t)(1*Hq + J) * 32;
    const uint2* wih_g = w_ihT  + (size_t)(2*Hq + J) * 32;
    const uint2* awih  = aw_ihT + (size_t)J * 32;
    const uint2* wwi_f = ww_ihT + (size_t)(0*Hq + J) * 32;
    const uint2* wwi_i = ww_ihT + (size_t)(1*Hq + J) * 32;
    const uint2* wwi_g = ww_ihT + (size_t)(2*Hq + J) * 32;
#pragma unroll
    for (int it = 0; it < 2; ++it){
      const int q = it * 16 + lane;
      Rwih_i[it] = wih_i[q];  Rwih_o[it] = wih_o[q];  Rwih_g[it] = wih_g[q];
      Rawih[it]  = awih[q];
      Rwwi_f[it] = wwi_f[q];  Rwwi_i[it] = wwi_i[q];  Rwwi_g[it] = wwi_g[q];
    }
  }

  const float b_i  = bias_b[J], b_o = bias_b[Hq + J], b_g = bias_b[2*Hq + J];
  const float ab_J = bias_ab[J];
  const float wb_f = bias_wb[J], wb_i = bias_wb[Hq + J], wb_g = bias_wb[2*Hq + J];

  float* out_h = out + (size_t)seq * Tq * Hq;            // hs block
  float* out_c = out + ((size_t)Bq + seq) * Tq * Hq;     // cs block

  __shared__ __align__(16) float shH[2][Hq];      // h by parity: shH[t&1] = h(t)
  __shared__ __align__(16) float sh_p0[Hq];
  __shared__ __align__(16) float sh_p1[Hq];
  __shared__ __align__(16) float shx[2][DCq];     // x(t) in shx[t&1]
  __shared__ __align__(16) float shxw0[2][DCq];   // xw(t) in shxw*[t&1]
  __shared__ __align__(16) float shxw1[2][DCq];

  // ---- pre-loop staging: zeros + x(0), xw(0) ----
  shH[0][i0] = 0.f; shH[0][i1] = 0.f;
  shH[1][i0] = 0.f; shH[1][i1] = 0.f;
  sh_p0[i0] = 0.f; sh_p0[i1] = 0.f;
  sh_p1[i0] = 0.f; sh_p1[i1] = 0.f;
  if (tid < DCq){
    shx[0][tid] = char_emb[((size_t)seq * Tq + 0) * DCq + tid];
  } else {
    const int k = tid - DCq;
    const int w0 = word_ids[(size_t)seq * Tq * 2 + 0];
    const int w1 = word_ids[(size_t)seq * Tq * 2 + 1];
    shxw0[0][k] = sense_table[(size_t)w0 * DCq + k];
    shxw1[0][k] = sense_table[(size_t)w1 * DCq + k];
  }
  __syncthreads();

  for (int t = 0; t < Tq; ++t){
    const int par = t & 1;
    const float* hprev = shH[par ^ 1];     // h(t-1)

    // ---- A1: i/o/g/xa matvecs (pend NOT needed) ----
    float a_i = 0.f, a_o = 0.f, a_g = 0.f, a_xa = 0.f;
#pragma unroll
    for (int it = 0; it < 8; ++it){
      const int k0 = it * 64 + lane * 4;
      float4 hv = *(const float4*)(hprev + k0);
      fma4(a_i, Rwhh_i[it], hv);
      fma4(a_o, Rwhh_o[it], hv);
      fma4(a_g, Rwhh_g[it], hv);
    }
#pragma unroll
    for (int it = 0; it < 2; ++it){
      const int k0 = it * 64 + lane * 4;
      float4 xv = *(const float4*)(shx[par] + k0);
      fma4(a_i,  Rwih_i[it], xv);
      fma4(a_o,  Rwih_o[it], xv);
      fma4(a_g,  Rwih_g[it], xv);
      fma4(a_xa, Rawih[it],  xv);
    }

    // ---- A2: poll pend for step t (usually already visible) ----
    if (t >= 3){
      const u64* p0 = pnd + ((size_t)(t & 3) * 2 + 0) * Hq;
      const u64* p1 = pnd + ((size_t)(t & 3) * 2 + 1) * Hq;
      const unsigned tg0 = (unsigned)t, tg1 = (unsigned)(t - 2);
      u64 a, b, c, d;
      for (;;){
        a = ld64(p0 + i0); b = ld64(p0 + i1);
        c = ld64(p1 + i0); d = ld64(p1 + i1);
        if (genof(a) >= tg0 && genof(b) >= tg0 &&
            genof(c) >= tg1 && genof(d) >= tg1) break;
      }
      sh_p0[i0] = valof(a); sh_p0[i1] = valof(b);
      sh_p1[i0] = valof(c); sh_p1[i1] = valof(d);
    } else if (t >= 1){
      const u64* p0 = pnd + ((size_t)(t & 3) * 2 + 0) * Hq;
      const unsigned tg0 = (unsigned)t;
      u64 a, b;
      for (;;){
        a = ld64(p0 + i0); b = ld64(p0 + i1);
        if (genof(a) >= tg0 && genof(b) >= tg0) break;
      }
      sh_p0[i0] = valof(a); sh_p0[i1] = valof(b);
      // sh_p1 stays zero (mask m1=0 for t<3)
    }
    __syncthreads();   // S1

    // ---- A3: alpha matvecs + gates ----
    float a_p0 = 0.f, a_p1 = 0.f;
#pragma unroll
    for (int it = 0; it < 8; ++it){
      const int k0 = it * 64 + lane * 4;
      float4 p0v = *(const float4*)(sh_p0 + k0);
      float4 p1v = *(const float4*)(sh_p1 + k0);
      fma4(a_p0, Rawhh[it], p0v);
      fma4(a_p1, Rawhh[it], p1v);
    }
    a_i  = red16(a_i);  a_o  = red16(a_o);  a_g  = red16(a_g);
    a_xa = red16(a_xa); a_p0 = red16(a_p0); a_p1 = red16(a_p1);

    const float gi = sigm(a_i + b_i);
    const float go = sigm(a_o + b_o);
    const float gg = tanhf(a_g + b_g);
    float c1;
    if (t == 0){
      c1 = gi * gg;                       // c_plain with c=0
    } else {
      const float base = a_xa + ab_J;
      const float ea0 = __expf(sigm(base + a_p0));   // m0=1 for t>=1
      const float ei  = __expf(gi);
      float num = ei * gg + ea0 * sh_p0[J];
      float den = ei + ea0;
      if (t >= 3){                                    // m1=1 for t>=3
        const float ea1 = __expf(sigm(base + a_p1));
        num += ea1 * sh_p1[J];
        den += ea1;
      }
      c1 = num / den;
    }
    const float h1 = go * tanhf(c1);
    if (lane == 0){
      pub64(hpub + (size_t)par * Hq + J, h1, (unsigned)(t + 1));  // value+gen, one 8B store
      out_h[(size_t)t * Hq + J] = h1;
      out_c[(size_t)t * Hq + J] = c1;
    }

    // ---- B2: stage x/xw(t+1) (overlaps poll) + poll full h(t) ----
    {
      const int tn = (t + 1 < Tq) ? t + 1 : t;
      if (tid < DCq){
        shx[par ^ 1][tid] = char_emb[((size_t)seq * Tq + tn) * DCq + tid];
      } else {
        const int k = tid - DCq;
        const int w0 = word_ids[((size_t)seq * Tq + tn) * 2 + 0];
        const int w1 = word_ids[((size_t)seq * Tq + tn) * 2 + 1];
        shxw0[par ^ 1][k] = sense_table[(size_t)w0 * DCq + k];
        shxw1[par ^ 1][k] = sense_table[(size_t)w1 * DCq + k];
      }
      const u64* hp = hpub + (size_t)par * Hq;
      const unsigned tg = (unsigned)(t + 1);
      u64 a, b;
      for (;;){
        a = ld64(hp + i0); b = ld64(hp + i1);
        if (genof(a) >= tg && genof(b) >= tg) break;
      }
      shH[par][i0] = valof(a); shH[par][i1] = valof(b);
    }
    __syncthreads();   // S2

    // ---- B3: word gates ----
    float r_f = 0.f, r_i = 0.f, r_g = 0.f;
    float x_f0 = 0.f, x_i0 = 0.f, x_g0 = 0.f, x_f1 = 0.f, x_i1 = 0.f, x_g1 = 0.f;
#pragma unroll
    for (int it = 0; it < 8; ++it){
      const int k0 = it * 64 + lane * 4;
      float4 hv = *(const float4*)(shH[par] + k0);
      fma4(r_f, Rwwh_f[it], hv);
      fma4(r_i, Rwwh_i[it], hv);
      fma4(r_g, Rwwh_g[it], hv);
    }
#pragma unroll
    for (int it = 0; it < 2; ++it){
      const int k0 = it * 64 + lane * 4;
      float4 x0 = *(const float4*)(shxw0[par] + k0);
      float4 x1 = *(const float4*)(shxw1[par] + k0);
      fma4(x_f0, Rwwi_f[it], x0);  fma4(x_f1, Rwwi_f[it], x1);
      fma4(x_i0, Rwwi_i[it], x0);  fma4(x_i1, Rwwi_i[it], x1);
      fma4(x_g0, Rwwi_g[it], x0);  fma4(x_g1, Rwwi_g[it], x1);
    }
    r_f  = red16(r_f);  r_i  = red16(r_i);  r_g  = red16(r_g);
    x_f0 = red16(x_f0); x_i0 = red16(x_i0); x_g0 = red16(x_g0);
    x_f1 = red16(x_f1); x_i1 = red16(x_i1); x_g1 = red16(x_g1);

    if (lane == 0){
      const float f0  = sigm(r_f + x_f0 + wb_f);
      const float iw0 = sigm(r_i + x_i0 + wb_i);
      const float g0  = tanhf(r_g + x_g0 + wb_g);
      const float cw0 = f0 * c1 + iw0 * g0;
      const float f1  = sigm(r_f + x_f1 + wb_f);
      const float iw1 = sigm(r_i + x_i1 + wb_i);
      const float g1  = tanhf(r_g + x_g1 + wb_g);
      const float cw1 = f1 * c1 + iw1 * g1;
      // gen = production step + 1; consumers poll p0>=t_c, p1>=t_c-2
      pub64(pnd + ((size_t)((t + 1) & 3) * 2 + 0) * Hq + J, cw0, (unsigned)(t + 1));
      pub64(pnd + ((size_t)((t + 3) & 3) * 2 + 1) * Hq + J, cw1, (unsigned)(t + 1));
    }
    // no barrier here: next A1 touches only shH[par^1]/shx[par^1] (disjoint),
    // next A2 LDS writes are fenced by S1; pend LDS buffers re-written only
    // after S2 of this step (cross-thread ordering via S1/S2 chain).
  }
}

extern "C" void kernel_launch(void* const* d_in, const int* in_sizes, int n_in,
                              void* d_out, int out_size, void* d_ws, size_t ws_size,
                              hipStream_t stream){
  const float* char_emb = (const float*)d_in[0];
  const int*   word_ids = (const int*)d_in[1];
  const float* sense    = (const float*)d_in[2];
  const float* w_ih     = (const float*)d_in[3];
  const float* w_hh     = (const float*)d_in[4];
  const float* bb       = (const float*)d_in[5];
  const float* aw_ih    = (const float*)d_in[6];
  const float* aw_hh    = (const float*)d_in[7];
  const float* ab       = (const float*)d_in[8];
  const float* ww_ih    = (const float*)d_in[9];
  const float* ww_hh    = (const float*)d_in[10];
  const float* wb       = (const float*)d_in[11];
  unsigned char* ws = (unsigned char*)d_ws;
  float* out = (float*)d_out;

  // zero all generation words (h_pub + pend) — ws is re-poisoned before every launch
  hipMemsetAsync(ws, 0, WIHT_OFF, stream);

  // one-time (per launch) weight convert+transpose to bf16
  transpose_bf16<<<512, NTHR, 0, stream>>>(w_ih,  (__hip_bfloat16*)(ws + WIHT_OFF),  7, 128*1536, 1536);
  transpose_bf16<<<512, NTHR, 0, stream>>>(w_hh,  (__hip_bfloat16*)(ws + WHHT_OFF),  9, 512*1536, 1536);
  transpose_bf16<<<512, NTHR, 0, stream>>>(aw_ih, (__hip_bfloat16*)(ws + AWIHT_OFF), 7, 128*512,  512);
  transpose_bf16<<<512, NTHR, 0, stream>>>(aw_hh, (__hip_bfloat16*)(ws + AWHHT_OFF), 9, 512*512,  512);
  transpose_bf16<<<512, NTHR, 0, stream>>>(ww_ih, (__hip_bfloat16*)(ws + WWIHT_OFF), 7, 128*1536, 1536);
  transpose_bf16<<<512, NTHR, 0, stream>>>(ww_hh, (__hip_bfloat16*)(ws + WWHHT_OFF), 9, 512*1536, 1536);

  dim3 grid(Bq, NWG);   // x = seq (XCD-local heuristic), y = wg slice
  lattice_main<<<grid, NTHR, 0, stream>>>(char_emb, word_ids, sense, bb, ab, wb, ws, out);
}

// Round 17
// 5447.143 us; speedup vs baseline: 1.7767x; 1.0287x over previous
//
#include <hip/hip_runtime.h>
#include <hip/hip_bf16.h>

// LatticeLSTM on MI355X — Round 17: R16 baseline + serial-path trims.
// Ledger (measured): R5/R16 = 5603-5607us (best, reproduced) | R7 = 18149
// (sc0-store stale) | R9 = 8245 (dual-scope 2x traffic) | R13 = 9678
// (2WG/CU lockstep) | R14 = 6717 (early-issue always-miss).
// Model: per step = serial cycle  h(t) -(RT)-> B3 -(RT)-> A3 -> h(t+1);
// only VALU BETWEEN arrival and publish is serial. This round shortens that:
//   1. xw (ww_ih) matvecs + their 6 red16 moved B3 -> B2 BEFORE the h-poll
//      (no early-issue! poll stays last with fresh loads — R5's validated
//      pattern). Fills the publish->visibility gap AND shortens B3.
//   2. polls use one 16B dwordx4 (sc1) per cell-pair instead of 2x8B:
//      half the requests; per-8B {val,gen} atomicity preserved (R9-verified
//      mechanics).
// Everything else identical to R16 (protocol, topology, ordering).
// Step layout (2 syncthreads/step, parity-double-buffered LDS):
//   A1: i/o/g/xa matvecs | A2: poll pend (16B loads) | S1
//   A3: alpha matvecs + gates; publish h | B2: stage x/xw(t+1) + xw matvecs
//   + poll h (16B) | S2 | B3: wwhh matvec + word gates; publish pend
// pmask data-independent: m0=(t>=1), m1=(t>=3); c_plain only at t=0.
// Progress needs all 256 WGs co-resident (1 WG/CU; LDS ~11KB, VGPR<256).

#define Bq 8
#define Tq 1024
#define DCq 128
#define Hq 512
#define NWG 32
#define NTHR 256

typedef unsigned long long u64;
typedef __attribute__((ext_vector_type(4))) unsigned int u32x4;

// ws byte offsets
#define HPUB_OFF  0u         // u64 h_pub[8][2][512]     = 65536
#define PENDP_OFF 65536u     // u64 pend[8][4][2][512]   = 262144
#define WIHT_OFF  327680u    // bf16 [1536][128]
#define WHHT_OFF  720896u    // bf16 [1536][512]
#define AWIHT_OFF 2293760u   // bf16 [512][128]
#define AWHHT_OFF 2424832u   // bf16 [512][512]
#define WWIHT_OFF 2949120u   // bf16 [1536][128]
#define WWHHT_OFF 3342336u   // bf16 [1536][512]  (end 4915200)

__device__ __forceinline__ float bflo(unsigned u){ return __uint_as_float(u << 16); }
__device__ __forceinline__ float bfhi(unsigned u){ return __uint_as_float(u & 0xffff0000u); }
__device__ __forceinline__ float sigm(float x){ return 1.0f / (1.0f + __expf(-x)); }

__device__ __forceinline__ void fma4(float& acc, uint2 w, float4 v){
  acc = fmaf(bflo(w.x), v.x, acc);
  acc = fmaf(bfhi(w.x), v.y, acc);
  acc = fmaf(bflo(w.y), v.z, acc);
  acc = fmaf(bfhi(w.y), v.w, acc);
}

__device__ __forceinline__ float red16(float x){
  x += __shfl_xor(x, 8, 16);
  x += __shfl_xor(x, 4, 16);
  x += __shfl_xor(x, 2, 16);
  x += __shfl_xor(x, 1, 16);
  return x;
}

__device__ __forceinline__ u64 pack64(float v, unsigned gen){
  return ((u64)gen << 32) | (u64)__float_as_uint(v);
}
__device__ __forceinline__ void pub64(u64* p, float v, unsigned gen){
  __hip_atomic_store(p, pack64(v, gen), __ATOMIC_RELAXED, __HIP_MEMORY_SCOPE_AGENT);
}

// 16B poll loads (sc1 = LLC coherence point, same as __hip_atomic_load agent).
// Layout: .x=val(i0) .y=gen(i0) .z=val(i1) .w=gen(i1). Address 16B-aligned
// (cell index i0 = tid*2 -> byte offset tid*16).
__device__ __forceinline__ u32x4 ld128_sc1(const u64* p){
  u32x4 r;
  asm volatile("global_load_dwordx4 %0, %1, off sc1\n\ts_waitcnt vmcnt(0)"
               : "=v"(r) : "v"(p) : "memory");
  return r;
}
__device__ __forceinline__ void ld128x2_sc1(const u64* p0, const u64* p1,
                                            u32x4& a, u32x4& b){
  asm volatile("global_load_dwordx4 %0, %2, off sc1\n\t"
               "global_load_dwordx4 %1, %3, off sc1\n\t"
               "s_waitcnt vmcnt(0)"
               : "=&v"(a), "=&v"(b) : "v"(p0), "v"(p1) : "memory");
}

// src [K][N] fp32 -> dst [N][K] bf16 (transpose + convert). K is pow2.
__global__ void transpose_bf16(const float* __restrict__ src, __hip_bfloat16* __restrict__ dst,
                               int kshift, int total, int N){
  const int K = 1 << kshift;
  for (int idx = blockIdx.x * blockDim.x + threadIdx.x; idx < total;
       idx += gridDim.x * blockDim.x){
    int n = idx >> kshift;
    int k = idx & (K - 1);
    dst[idx] = __float2bfloat16(src[(size_t)k * N + n]);
  }
}

__global__ void __launch_bounds__(NTHR, 1)
lattice_main(const float* __restrict__ char_emb,
             const int*   __restrict__ word_ids,
             const float* __restrict__ sense_table,
             const float* __restrict__ bias_b,
             const float* __restrict__ bias_ab,
             const float* __restrict__ bias_wb,
             unsigned char* __restrict__ ws,
             float* __restrict__ out)
{
  const int seq  = blockIdx.x;
  const int wg   = blockIdx.y;
  const int tid  = threadIdx.x;
  const int grp  = tid >> 4;
  const int lane = tid & 15;
  const int J    = wg * 16 + grp;               // owned H column
  const int i0   = tid * 2, i1 = tid * 2 + 1;   // poll cells (one 16B pair)

  u64* hpub = (u64*)(ws + HPUB_OFF)  + (size_t)seq * 2 * Hq;      // [parity][col]
  u64* pnd  = (u64*)(ws + PENDP_OFF) + (size_t)seq * 4 * 2 * Hq;  // [slot][k][col]

  const uint2* w_ihT  = (const uint2*)(ws + WIHT_OFF);
  const uint2* w_hhT  = (const uint2*)(ws + WHHT_OFF);
  const uint2* aw_ihT = (const uint2*)(ws + AWIHT_OFF);
  const uint2* aw_hhT = (const uint2*)(ws + AWHHT_OFF);
  const uint2* ww_ihT = (const uint2*)(ws + WWIHT_OFF);
  const uint2* ww_hhT = (const uint2*)(ws + WWHHT_OFF);

  // ---- hoist ALL weights into registers (addresses are t-invariant) ----
  uint2 Rwhh_i[8], Rwhh_o[8], Rwhh_g[8], Rawhh[8];
  uint2 Rwwh_f[8], Rwwh_i[8], Rwwh_g[8];
  uint2 Rwih_i[2], Rwih_o[2], Rwih_g[2], Rawih[2];
  uint2 Rwwi_f[2], Rwwi_i[2], Rwwi_g[2];
  {
    const uint2* whh_i = w_hhT  + (size_t)(0*Hq + J) * 128;
    const uint2* whh_o = w_hhT  + (size_t)(1*Hq + J) * 128;
    const uint2* whh_g = w_hhT  + (size_t)(2*Hq + J) * 128;
    const uint2* awhh  = aw_hhT + (size_t)J * 128;
    const uint2* wwh_f = ww_hhT + (size_t)(0*Hq + J) * 128;
    const uint2* wwh_i = ww_hhT + (size_t)(1*Hq + J) * 128;
    const uint2* wwh_g = ww_hhT + (size_t)(2*Hq + J) * 128;
#pragma unroll
    for (int it = 0; it < 8; ++it){
      const int q = it * 16 + lane;
      Rwhh_i[it] = whh_i[q];  Rwhh_o[it] = whh_o[q];  Rwhh_g[it] = whh_g[q];
      Rawhh[it]  = awhh[q];
      Rwwh_f[it] = wwh_f[q];  Rwwh_i[it] = wwh_i[q];  Rwwh_g[it] = wwh_g[q];
    }
    const uint2* wih_i = w_ihT  + (size_t)(0*Hq + J) * 32;
    const uint2* wih_o = w_ihT  + (size_t)(1*Hq + J) * 32;
    const uint2* wih_g = w_ihT  + (size_t)(2*Hq + J) * 32;
    const uint2* awih  = aw_ihT + (size_t)J * 32;
    const uint2* wwi_f = ww_ihT + (size_t)(0*Hq + J) * 32;
    const uint2* wwi_i = ww_ihT + (size_t)(1*Hq + J) * 32;
    const uint2* wwi_g = ww_ihT + (size_t)(2*Hq + J) * 32;
#pragma unroll
    for (int it = 0; it < 2; ++it){
      const int q = it * 16 + lane;
      Rwih_i[it] = wih_i[q];  Rwih_o[it] = wih_o[q];  Rwih_g[it] = wih_g[q];
      Rawih[it]  = awih[q];
      Rwwi_f[it] = wwi_f[q];  Rwwi_i[it] = wwi_i[q];  Rwwi_g[it] = wwi_g[q];
    }
  }

  const float b_i  = bias_b[J], b_o = bias_b[Hq + J], b_g = bias_b[2*Hq + J];
  const float ab_J = bias_ab[J];
  const float wb_f = bias_wb[J], wb_i = bias_wb[Hq + J], wb_g = bias_wb[2*Hq + J];

  float* out_h = out + (size_t)seq * Tq * Hq;            // hs block
  float* out_c = out + ((size_t)Bq + seq) * Tq * Hq;     // cs block

  __shared__ __align__(16) float shH[2][Hq];      // h by parity: shH[t&1] = h(t)
  __shared__ __align__(16) float sh_p0[Hq];
  __shared__ __align__(16) float sh_p1[Hq];
  __shared__ __align__(16) float shx[2][DCq];     // x(t) in shx[t&1]
  __shared__ __align__(16) float shxw0[2][DCq];   // xw(t) in shxw*[t&1]
  __shared__ __align__(16) float shxw1[2][DCq];

  // ---- pre-loop staging: zeros + x(0), xw(0) ----
  shH[0][i0] = 0.f; shH[0][i1] = 0.f;
  shH[1][i0] = 0.f; shH[1][i1] = 0.f;
  sh_p0[i0] = 0.f; sh_p0[i1] = 0.f;
  sh_p1[i0] = 0.f; sh_p1[i1] = 0.f;
  if (tid < DCq){
    shx[0][tid] = char_emb[((size_t)seq * Tq + 0) * DCq + tid];
  } else {
    const int k = tid - DCq;
    const int w0 = word_ids[(size_t)seq * Tq * 2 + 0];
    const int w1 = word_ids[(size_t)seq * Tq * 2 + 1];
    shxw0[0][k] = sense_table[(size_t)w0 * DCq + k];
    shxw1[0][k] = sense_table[(size_t)w1 * DCq + k];
  }
  __syncthreads();

  for (int t = 0; t < Tq; ++t){
    const int par = t & 1;
    const float* hprev = shH[par ^ 1];     // h(t-1)

    // ---- A1: i/o/g/xa matvecs (pend NOT needed) ----
    float a_i = 0.f, a_o = 0.f, a_g = 0.f, a_xa = 0.f;
#pragma unroll
    for (int it = 0; it < 8; ++it){
      const int k0 = it * 64 + lane * 4;
      float4 hv = *(const float4*)(hprev + k0);
      fma4(a_i, Rwhh_i[it], hv);
      fma4(a_o, Rwhh_o[it], hv);
      fma4(a_g, Rwhh_g[it], hv);
    }
#pragma unroll
    for (int it = 0; it < 2; ++it){
      const int k0 = it * 64 + lane * 4;
      float4 xv = *(const float4*)(shx[par] + k0);
      fma4(a_i,  Rwih_i[it], xv);
      fma4(a_o,  Rwih_o[it], xv);
      fma4(a_g,  Rwih_g[it], xv);
      fma4(a_xa, Rawih[it],  xv);
    }

    // ---- A2: poll pend for step t (16B loads; usually already visible) ----
    if (t >= 3){
      const u64* p0 = pnd + ((size_t)(t & 3) * 2 + 0) * Hq;
      const u64* p1 = pnd + ((size_t)(t & 3) * 2 + 1) * Hq;
      const unsigned tg0 = (unsigned)t, tg1 = (unsigned)(t - 2);
      u32x4 a, c;
      for (;;){
        ld128x2_sc1(p0 + i0, p1 + i0, a, c);
        if (a.y >= tg0 && a.w >= tg0 && c.y >= tg1 && c.w >= tg1) break;
      }
      sh_p0[i0] = __uint_as_float(a.x); sh_p0[i1] = __uint_as_float(a.z);
      sh_p1[i0] = __uint_as_float(c.x); sh_p1[i1] = __uint_as_float(c.z);
    } else if (t >= 1){
      const u64* p0 = pnd + ((size_t)(t & 3) * 2 + 0) * Hq;
      const unsigned tg0 = (unsigned)t;
      u32x4 a;
      for (;;){
        a = ld128_sc1(p0 + i0);
        if (a.y >= tg0 && a.w >= tg0) break;
      }
      sh_p0[i0] = __uint_as_float(a.x); sh_p0[i1] = __uint_as_float(a.z);
      // sh_p1 stays zero (mask m1=0 for t<3)
    }
    __syncthreads();   // S1

    // ---- A3: alpha matvecs + gates ----
    float a_p0 = 0.f, a_p1 = 0.f;
#pragma unroll
    for (int it = 0; it < 8; ++it){
      const int k0 = it * 64 + lane * 4;
      float4 p0v = *(const float4*)(sh_p0 + k0);
      float4 p1v = *(const float4*)(sh_p1 + k0);
      fma4(a_p0, Rawhh[it], p0v);
      fma4(a_p1, Rawhh[it], p1v);
    }
    a_i  = red16(a_i);  a_o  = red16(a_o);  a_g  = red16(a_g);
    a_xa = red16(a_xa); a_p0 = red16(a_p0); a_p1 = red16(a_p1);

    const float gi = sigm(a_i + b_i);
    const float go = sigm(a_o + b_o);
    const float gg = tanhf(a_g + b_g);
    float c1;
    if (t == 0){
      c1 = gi * gg;                       // c_plain with c=0
    } else {
      const float base = a_xa + ab_J;
      const float ea0 = __expf(sigm(base + a_p0));   // m0=1 for t>=1
      const float ei  = __expf(gi);
      float num = ei * gg + ea0 * sh_p0[J];
      float den = ei + ea0;
      if (t >= 3){                                    // m1=1 for t>=3
        const float ea1 = __expf(sigm(base + a_p1));
        num += ea1 * sh_p1[J];
        den += ea1;
      }
      c1 = num / den;
    }
    const float h1 = go * tanhf(c1);
    if (lane == 0){
      pub64(hpub + (size_t)par * Hq + J, h1, (unsigned)(t + 1));  // value+gen, one 8B store
      out_h[(size_t)t * Hq + J] = h1;
      out_c[(size_t)t * Hq + J] = c1;
    }

    // ---- B2: stage x/xw(t+1) + xw matvecs (h-independent) + poll h(t) ----
    float x_f0 = 0.f, x_i0 = 0.f, x_g0 = 0.f, x_f1 = 0.f, x_i1 = 0.f, x_g1 = 0.f;
    {
      const int tn = (t + 1 < Tq) ? t + 1 : t;
      if (tid < DCq){
        shx[par ^ 1][tid] = char_emb[((size_t)seq * Tq + tn) * DCq + tid];
      } else {
        const int k = tid - DCq;
        const int w0 = word_ids[((size_t)seq * Tq + tn) * 2 + 0];
        const int w1 = word_ids[((size_t)seq * Tq + tn) * 2 + 1];
        shxw0[par ^ 1][k] = sense_table[(size_t)w0 * DCq + k];
        shxw1[par ^ 1][k] = sense_table[(size_t)w1 * DCq + k];
      }
      // xw matvecs (read shxw*[par], staged at t-1): fill the publish->
      // visibility gap of h AND shorten B3's serial segment.
#pragma unroll
      for (int it = 0; it < 2; ++it){
        const int k0 = it * 64 + lane * 4;
        float4 x0 = *(const float4*)(shxw0[par] + k0);
        float4 x1 = *(const float4*)(shxw1[par] + k0);
        fma4(x_f0, Rwwi_f[it], x0);  fma4(x_f1, Rwwi_f[it], x1);
        fma4(x_i0, Rwwi_i[it], x0);  fma4(x_i1, Rwwi_i[it], x1);
        fma4(x_g0, Rwwi_g[it], x0);  fma4(x_g1, Rwwi_g[it], x1);
      }
      x_f0 = red16(x_f0); x_i0 = red16(x_i0); x_g0 = red16(x_g0);
      x_f1 = red16(x_f1); x_i1 = red16(x_i1); x_g1 = red16(x_g1);

      // poll full h(t) — the ONE exposed round trip (LAST, fresh loads)
      const u64* hp = hpub + (size_t)par * Hq;
      const unsigned tg = (unsigned)(t + 1);
      u32x4 a;
      for (;;){
        a = ld128_sc1(hp + i0);
        if (a.y >= tg && a.w >= tg) break;
      }
      shH[par][i0] = __uint_as_float(a.x); shH[par][i1] = __uint_as_float(a.z);
    }
    __syncthreads();   // S2

    // ---- B3: h-dependent word gates + publish pend ----
    float r_f = 0.f, r_i = 0.f, r_g = 0.f;
#pragma unroll
    for (int it = 0; it < 8; ++it){
      const int k0 = it * 64 + lane * 4;
      float4 hv = *(const float4*)(shH[par] + k0);
      fma4(r_f, Rwwh_f[it], hv);
      fma4(r_i, Rwwh_i[it], hv);
      fma4(r_g, Rwwh_g[it], hv);
    }
    r_f = red16(r_f);  r_i = red16(r_i);  r_g = red16(r_g);

    if (lane == 0){
      const float f0  = sigm(r_f + x_f0 + wb_f);
      const float iw0 = sigm(r_i + x_i0 + wb_i);
      const float g0  = tanhf(r_g + x_g0 + wb_g);
      const float cw0 = f0 * c1 + iw0 * g0;
      // cw0 (len-2 word, consumed at t+1: tightest slack) published first
      pub64(pnd + ((size_t)((t + 1) & 3) * 2 + 0) * Hq + J, cw0, (unsigned)(t + 1));
      const float f1  = sigm(r_f + x_f1 + wb_f);
      const float iw1 = sigm(r_i + x_i1 + wb_i);
      const float g1  = tanhf(r_g + x_g1 + wb_g);
      const float cw1 = f1 * c1 + iw1 * g1;
      pub64(pnd + ((size_t)((t + 3) & 3) * 2 + 1) * Hq + J, cw1, (unsigned)(t + 1));
    }
    // no barrier here: next A1 touches only shH[par^1]/shx[par^1] (disjoint),
    // next A2 LDS writes are fenced by S1; pend LDS buffers re-written only
    // after S2 of this step (cross-thread ordering via S1/S2 chain).
  }
}

extern "C" void kernel_launch(void* const* d_in, const int* in_sizes, int n_in,
                              void* d_out, int out_size, void* d_ws, size_t ws_size,
                              hipStream_t stream){
  const float* char_emb = (const float*)d_in[0];
  const int*   word_ids = (const int*)d_in[1];
  const float* sense    = (const float*)d_in[2];
  const float* w_ih     = (const float*)d_in[3];
  const float* w_hh     = (const float*)d_in[4];
  const float* bb       = (const float*)d_in[5];
  const float* aw_ih    = (const float*)d_in[6];
  const float* aw_hh    = (const float*)d_in[7];
  const float* ab       = (const float*)d_in[8];
  const float* ww_ih    = (const float*)d_in[9];
  const float* ww_hh    = (const float*)d_in[10];
  const float* wb       = (const float*)d_in[11];
  unsigned char* ws = (unsigned char*)d_ws;
  float* out = (float*)d_out;

  // zero all generation words (h_pub + pend) — ws is re-poisoned before every launch
  hipMemsetAsync(ws, 0, WIHT_OFF, stream);

  // one-time (per launch) weight convert+transpose to bf16
  transpose_bf16<<<512, NTHR, 0, stream>>>(w_ih,  (__hip_bfloat16*)(ws + WIHT_OFF),  7, 128*1536, 1536);
  transpose_bf16<<<512, NTHR, 0, stream>>>(w_hh,  (__hip_bfloat16*)(ws + WHHT_OFF),  9, 512*1536, 1536);
  transpose_bf16<<<512, NTHR, 0, stream>>>(aw_ih, (__hip_bfloat16*)(ws + AWIHT_OFF), 7, 128*512,  512);
  transpose_bf16<<<512, NTHR, 0, stream>>>(aw_hh, (__hip_bfloat16*)(ws + AWHHT_OFF), 9, 512*512,  512);
  transpose_bf16<<<512, NTHR, 0, stream>>>(ww_ih, (__hip_bfloat16*)(ws + WWIHT_OFF), 7, 128*1536, 1536);
  transpose_bf16<<<512, NTHR, 0, stream>>>(ww_hh, (__hip_bfloat16*)(ws + WWHHT_OFF), 9, 512*1536, 1536);

  dim3 grid(Bq, NWG);   // x = seq (XCD-local heuristic), y = wg slice
  lattice_main<<<grid, NTHR, 0, stream>>>(char_emb, word_ids, sense, bb, ab, wb, ws, out);
}

// Round 18
// 5376.283 us; speedup vs baseline: 1.8001x; 1.0132x over previous
//
#include <hip/hip_runtime.h>
#include <hip/hip_bf16.h>

// LatticeLSTM on MI355X — Round 18: R17 + A-phase pend-independent hoist.
// Ledger (measured): R17 = 5447us (best) | R5/R16 = 5603-5607 | R14 = 6717
// (early-issue) | R9 = 8245 (dual-scope) | R13 = 9678 (2WG/CU) | R7 = 18149
// (sc0 stale). Model: per step = serial cycle h(t) -(RT)-> B3 -(RT)-> A3 ->
// h(t+1); only VALU BETWEEN arrival and publish is serial. R17 proved the
// trims work (xw hoist + 16B polls: -156us, FETCH 113->83MB).
// R18 hoists the remaining pend-INDEPENDENT A-phase work off the serial path:
//   red16(a_i/a_o/a_g/a_xa), gi/go/gg (sigm/tanh), ei=exp(gi), base — all
//   computed BEFORE/DURING the A2 spin (they only need A1 results). After S1
//   only {alpha matvec, red16 x2, ea0/ea1, num/den, h1} remain serial.
// Everything else identical to R17.
// Step layout (2 syncthreads/step, parity-double-buffered LDS):
//   A1 matvecs | A2: pre-reduce+gates, poll pend (16B) | S1
//   A3: alpha matvec + combine; publish h | B2: stage x/xw(t+1) + xw matvecs
//   + poll h (16B) | S2 | B3: wwhh matvec + word gates; publish pend
// pmask data-independent: m0=(t>=1), m1=(t>=3); c_plain only at t=0.
// Progress needs all 256 WGs co-resident (1 WG/CU; LDS ~11KB, VGPR<256).

#define Bq 8
#define Tq 1024
#define DCq 128
#define Hq 512
#define NWG 32
#define NTHR 256

typedef unsigned long long u64;
typedef __attribute__((ext_vector_type(4))) unsigned int u32x4;

// ws byte offsets
#define HPUB_OFF  0u         // u64 h_pub[8][2][512]     = 65536
#define PENDP_OFF 65536u     // u64 pend[8][4][2][512]   = 262144
#define WIHT_OFF  327680u    // bf16 [1536][128]
#define WHHT_OFF  720896u    // bf16 [1536][512]
#define AWIHT_OFF 2293760u   // bf16 [512][128]
#define AWHHT_OFF 2424832u   // bf16 [512][512]
#define WWIHT_OFF 2949120u   // bf16 [1536][128]
#define WWHHT_OFF 3342336u   // bf16 [1536][512]  (end 4915200)

__device__ __forceinline__ float bflo(unsigned u){ return __uint_as_float(u << 16); }
__device__ __forceinline__ float bfhi(unsigned u){ return __uint_as_float(u & 0xffff0000u); }
__device__ __forceinline__ float sigm(float x){ return 1.0f / (1.0f + __expf(-x)); }

__device__ __forceinline__ void fma4(float& acc, uint2 w, float4 v){
  acc = fmaf(bflo(w.x), v.x, acc);
  acc = fmaf(bfhi(w.x), v.y, acc);
  acc = fmaf(bflo(w.y), v.z, acc);
  acc = fmaf(bfhi(w.y), v.w, acc);
}

__device__ __forceinline__ float red16(float x){
  x += __shfl_xor(x, 8, 16);
  x += __shfl_xor(x, 4, 16);
  x += __shfl_xor(x, 2, 16);
  x += __shfl_xor(x, 1, 16);
  return x;
}

__device__ __forceinline__ u64 pack64(float v, unsigned gen){
  return ((u64)gen << 32) | (u64)__float_as_uint(v);
}
__device__ __forceinline__ void pub64(u64* p, float v, unsigned gen){
  __hip_atomic_store(p, pack64(v, gen), __ATOMIC_RELAXED, __HIP_MEMORY_SCOPE_AGENT);
}

// 16B poll loads (sc1 = LLC coherence point, same as __hip_atomic_load agent).
// Layout: .x=val(i0) .y=gen(i0) .z=val(i1) .w=gen(i1). Address 16B-aligned
// (cell index i0 = tid*2 -> byte offset tid*16).
__device__ __forceinline__ u32x4 ld128_sc1(const u64* p){
  u32x4 r;
  asm volatile("global_load_dwordx4 %0, %1, off sc1\n\ts_waitcnt vmcnt(0)"
               : "=v"(r) : "v"(p) : "memory");
  return r;
}
__device__ __forceinline__ void ld128x2_sc1(const u64* p0, const u64* p1,
                                            u32x4& a, u32x4& b){
  asm volatile("global_load_dwordx4 %0, %2, off sc1\n\t"
               "global_load_dwordx4 %1, %3, off sc1\n\t"
               "s_waitcnt vmcnt(0)"
               : "=&v"(a), "=&v"(b) : "v"(p0), "v"(p1) : "memory");
}

// src [K][N] fp32 -> dst [N][K] bf16 (transpose + convert). K is pow2.
__global__ void transpose_bf16(const float* __restrict__ src, __hip_bfloat16* __restrict__ dst,
                               int kshift, int total, int N){
  const int K = 1 << kshift;
  for (int idx = blockIdx.x * blockDim.x + threadIdx.x; idx < total;
       idx += gridDim.x * blockDim.x){
    int n = idx >> kshift;
    int k = idx & (K - 1);
    dst[idx] = __float2bfloat16(src[(size_t)k * N + n]);
  }
}

__global__ void __launch_bounds__(NTHR, 1)
lattice_main(const float* __restrict__ char_emb,
             const int*   __restrict__ word_ids,
             const float* __restrict__ sense_table,
             const float* __restrict__ bias_b,
             const float* __restrict__ bias_ab,
             const float* __restrict__ bias_wb,
             unsigned char* __restrict__ ws,
             float* __restrict__ out)
{
  const int seq  = blockIdx.x;
  const int wg   = blockIdx.y;
  const int tid  = threadIdx.x;
  const int grp  = tid >> 4;
  const int lane = tid & 15;
  const int J    = wg * 16 + grp;               // owned H column
  const int i0   = tid * 2, i1 = tid * 2 + 1;   // poll cells (one 16B pair)

  u64* hpub = (u64*)(ws + HPUB_OFF)  + (size_t)seq * 2 * Hq;      // [parity][col]
  u64* pnd  = (u64*)(ws + PENDP_OFF) + (size_t)seq * 4 * 2 * Hq;  // [slot][k][col]

  const uint2* w_ihT  = (const uint2*)(ws + WIHT_OFF);
  const uint2* w_hhT  = (const uint2*)(ws + WHHT_OFF);
  const uint2* aw_ihT = (const uint2*)(ws + AWIHT_OFF);
  const uint2* aw_hhT = (const uint2*)(ws + AWHHT_OFF);
  const uint2* ww_ihT = (const uint2*)(ws + WWIHT_OFF);
  const uint2* ww_hhT = (const uint2*)(ws + WWHHT_OFF);

  // ---- hoist ALL weights into registers (addresses are t-invariant) ----
  uint2 Rwhh_i[8], Rwhh_o[8], Rwhh_g[8], Rawhh[8];
  uint2 Rwwh_f[8], Rwwh_i[8], Rwwh_g[8];
  uint2 Rwih_i[2], Rwih_o[2], Rwih_g[2], Rawih[2];
  uint2 Rwwi_f[2], Rwwi_i[2], Rwwi_g[2];
  {
    const uint2* whh_i = w_hhT  + (size_t)(0*Hq + J) * 128;
    const uint2* whh_o = w_hhT  + (size_t)(1*Hq + J) * 128;
    const uint2* whh_g = w_hhT  + (size_t)(2*Hq + J) * 128;
    const uint2* awhh  = aw_hhT + (size_t)J * 128;
    const uint2* wwh_f = ww_hhT + (size_t)(0*Hq + J) * 128;
    const uint2* wwh_i = ww_hhT + (size_t)(1*Hq + J) * 128;
    const uint2* wwh_g = ww_hhT + (size_t)(2*Hq + J) * 128;
#pragma unroll
    for (int it = 0; it < 8; ++it){
      const int q = it * 16 + lane;
      Rwhh_i[it] = whh_i[q];  Rwhh_o[it] = whh_o[q];  Rwhh_g[it] = whh_g[q];
      Rawhh[it]  = awhh[q];
      Rwwh_f[it] = wwh_f[q];  Rwwh_i[it] = wwh_i[q];  Rwwh_g[it] = wwh_g[q];
    }
    const uint2* wih_i = w_ihT  + (size_t)(0*Hq + J) * 32;
    const uint2* wih_o = w_ihT  + (size_t)(1*Hq + J) * 32;
    const uint2* wih_g = w_ihT  + (size_t)(2*Hq + J) * 32;
    const uint2* awih  = aw_ihT + (size_t)J * 32;
    const uint2* wwi_f = ww_ihT + (size_t)(0*Hq + J) * 32;
    const uint2* wwi_i = ww_ihT + (size_t)(1*Hq + J) * 32;
    const uint2* wwi_g = ww_ihT + (size_t)(2*Hq + J) * 32;
#pragma unroll
    for (int it = 0; it < 2; ++it){
      const int q = it * 16 + lane;
      Rwih_i[it] = wih_i[q];  Rwih_o[it] = wih_o[q];  Rwih_g[it] = wih_g[q];
      Rawih[it]  = awih[q];
      Rwwi_f[it] = wwi_f[q];  Rwwi_i[it] = wwi_i[q];  Rwwi_g[it] = wwi_g[q];
    }
  }

  const float b_i  = bias_b[J], b_o = bias_b[Hq + J], b_g = bias_b[2*Hq + J];
  const float ab_J = bias_ab[J];
  const float wb_f = bias_wb[J], wb_i = bias_wb[Hq + J], wb_g = bias_wb[2*Hq + J];

  float* out_h = out + (size_t)seq * Tq * Hq;            // hs block
  float* out_c = out + ((size_t)Bq + seq) * Tq * Hq;     // cs block

  __shared__ __align__(16) float shH[2][Hq];      // h by parity: shH[t&1] = h(t)
  __shared__ __align__(16) float sh_p0[Hq];
  __shared__ __align__(16) float sh_p1[Hq];
  __shared__ __align__(16) float shx[2][DCq];     // x(t) in shx[t&1]
  __shared__ __align__(16) float shxw0[2][DCq];   // xw(t) in shxw*[t&1]
  __shared__ __align__(16) float shxw1[2][DCq];

  // ---- pre-loop staging: zeros + x(0), xw(0) ----
  shH[0][i0] = 0.f; shH[0][i1] = 0.f;
  shH[1][i0] = 0.f; shH[1][i1] = 0.f;
  sh_p0[i0] = 0.f; sh_p0[i1] = 0.f;
  sh_p1[i0] = 0.f; sh_p1[i1] = 0.f;
  if (tid < DCq){
    shx[0][tid] = char_emb[((size_t)seq * Tq + 0) * DCq + tid];
  } else {
    const int k = tid - DCq;
    const int w0 = word_ids[(size_t)seq * Tq * 2 + 0];
    const int w1 = word_ids[(size_t)seq * Tq * 2 + 1];
    shxw0[0][k] = sense_table[(size_t)w0 * DCq + k];
    shxw1[0][k] = sense_table[(size_t)w1 * DCq + k];
  }
  __syncthreads();

  for (int t = 0; t < Tq; ++t){
    const int par = t & 1;
    const float* hprev = shH[par ^ 1];     // h(t-1)

    // ---- A1: i/o/g/xa matvecs (pend NOT needed) ----
    float a_i = 0.f, a_o = 0.f, a_g = 0.f, a_xa = 0.f;
#pragma unroll
    for (int it = 0; it < 8; ++it){
      const int k0 = it * 64 + lane * 4;
      float4 hv = *(const float4*)(hprev + k0);
      fma4(a_i, Rwhh_i[it], hv);
      fma4(a_o, Rwhh_o[it], hv);
      fma4(a_g, Rwhh_g[it], hv);
    }
#pragma unroll
    for (int it = 0; it < 2; ++it){
      const int k0 = it * 64 + lane * 4;
      float4 xv = *(const float4*)(shx[par] + k0);
      fma4(a_i,  Rwih_i[it], xv);
      fma4(a_o,  Rwih_o[it], xv);
      fma4(a_g,  Rwih_g[it], xv);
      fma4(a_xa, Rawih[it],  xv);
    }

    // ---- A2a: pend-independent reductions + gates (off the serial path) ----
    a_i  = red16(a_i);  a_o = red16(a_o);  a_g = red16(a_g);  a_xa = red16(a_xa);
    const float gi   = sigm(a_i + b_i);
    const float go   = sigm(a_o + b_o);
    const float gg   = tanhf(a_g + b_g);
    const float ei   = __expf(gi);
    const float base = a_xa + ab_J;

    // ---- A2b: poll pend for step t (16B loads; usually already visible) ----
    if (t >= 3){
      const u64* p0 = pnd + ((size_t)(t & 3) * 2 + 0) * Hq;
      const u64* p1 = pnd + ((size_t)(t & 3) * 2 + 1) * Hq;
      const unsigned tg0 = (unsigned)t, tg1 = (unsigned)(t - 2);
      u32x4 a, c;
      for (;;){
        ld128x2_sc1(p0 + i0, p1 + i0, a, c);
        if (a.y >= tg0 && a.w >= tg0 && c.y >= tg1 && c.w >= tg1) break;
      }
      sh_p0[i0] = __uint_as_float(a.x); sh_p0[i1] = __uint_as_float(a.z);
      sh_p1[i0] = __uint_as_float(c.x); sh_p1[i1] = __uint_as_float(c.z);
    } else if (t >= 1){
      const u64* p0 = pnd + ((size_t)(t & 3) * 2 + 0) * Hq;
      const unsigned tg0 = (unsigned)t;
      u32x4 a;
      for (;;){
        a = ld128_sc1(p0 + i0);
        if (a.y >= tg0 && a.w >= tg0) break;
      }
      sh_p0[i0] = __uint_as_float(a.x); sh_p0[i1] = __uint_as_float(a.z);
      // sh_p1 stays zero (mask m1=0 for t<3)
    }
    __syncthreads();   // S1

    // ---- A3: alpha matvec + combine (only pend-dependent work remains) ----
    float a_p0 = 0.f, a_p1 = 0.f;
#pragma unroll
    for (int it = 0; it < 8; ++it){
      const int k0 = it * 64 + lane * 4;
      float4 p0v = *(const float4*)(sh_p0 + k0);
      float4 p1v = *(const float4*)(sh_p1 + k0);
      fma4(a_p0, Rawhh[it], p0v);
      fma4(a_p1, Rawhh[it], p1v);
    }
    a_p0 = red16(a_p0); a_p1 = red16(a_p1);

    float c1;
    if (t == 0){
      c1 = gi * gg;                       // c_plain with c=0
    } else {
      const float ea0 = __expf(sigm(base + a_p0));   // m0=1 for t>=1
      float num = ei * gg + ea0 * sh_p0[J];
      float den = ei + ea0;
      if (t >= 3){                                    // m1=1 for t>=3
        const float ea1 = __expf(sigm(base + a_p1));
        num += ea1 * sh_p1[J];
        den += ea1;
      }
      c1 = num / den;
    }
    const float h1 = go * tanhf(c1);
    if (lane == 0){
      pub64(hpub + (size_t)par * Hq + J, h1, (unsigned)(t + 1));  // value+gen, one 8B store
      out_h[(size_t)t * Hq + J] = h1;
      out_c[(size_t)t * Hq + J] = c1;
    }

    // ---- B2: stage x/xw(t+1) + xw matvecs (h-independent) + poll h(t) ----
    float x_f0 = 0.f, x_i0 = 0.f, x_g0 = 0.f, x_f1 = 0.f, x_i1 = 0.f, x_g1 = 0.f;
    {
      const int tn = (t + 1 < Tq) ? t + 1 : t;
      if (tid < DCq){
        shx[par ^ 1][tid] = char_emb[((size_t)seq * Tq + tn) * DCq + tid];
      } else {
        const int k = tid - DCq;
        const int w0 = word_ids[((size_t)seq * Tq + tn) * 2 + 0];
        const int w1 = word_ids[((size_t)seq * Tq + tn) * 2 + 1];
        shxw0[par ^ 1][k] = sense_table[(size_t)w0 * DCq + k];
        shxw1[par ^ 1][k] = sense_table[(size_t)w1 * DCq + k];
      }
      // xw matvecs (read shxw*[par], staged at t-1): fill the publish->
      // visibility gap of h AND shorten B3's serial segment.
#pragma unroll
      for (int it = 0; it < 2; ++it){
        const int k0 = it * 64 + lane * 4;
        float4 x0 = *(const float4*)(shxw0[par] + k0);
        float4 x1 = *(const float4*)(shxw1[par] + k0);
        fma4(x_f0, Rwwi_f[it], x0);  fma4(x_f1, Rwwi_f[it], x1);
        fma4(x_i0, Rwwi_i[it], x0);  fma4(x_i1, Rwwi_i[it], x1);
        fma4(x_g0, Rwwi_g[it], x0);  fma4(x_g1, Rwwi_g[it], x1);
      }
      x_f0 = red16(x_f0); x_i0 = red16(x_i0); x_g0 = red16(x_g0);
      x_f1 = red16(x_f1); x_i1 = red16(x_i1); x_g1 = red16(x_g1);

      // poll full h(t) — the ONE exposed round trip (LAST, fresh loads)
      const u64* hp = hpub + (size_t)par * Hq;
      const unsigned tg = (unsigned)(t + 1);
      u32x4 a;
      for (;;){
        a = ld128_sc1(hp + i0);
        if (a.y >= tg && a.w >= tg) break;
      }
      shH[par][i0] = __uint_as_float(a.x); shH[par][i1] = __uint_as_float(a.z);
    }
    __syncthreads();   // S2

    // ---- B3: h-dependent word gates + publish pend ----
    float r_f = 0.f, r_i = 0.f, r_g = 0.f;
#pragma unroll
    for (int it = 0; it < 8; ++it){
      const int k0 = it * 64 + lane * 4;
      float4 hv = *(const float4*)(shH[par] + k0);
      fma4(r_f, Rwwh_f[it], hv);
      fma4(r_i, Rwwh_i[it], hv);
      fma4(r_g, Rwwh_g[it], hv);
    }
    r_f = red16(r_f);  r_i = red16(r_i);  r_g = red16(r_g);

    if (lane == 0){
      const float f0  = sigm(r_f + x_f0 + wb_f);
      const float iw0 = sigm(r_i + x_i0 + wb_i);
      const float g0  = tanhf(r_g + x_g0 + wb_g);
      const float cw0 = f0 * c1 + iw0 * g0;
      // cw0 (len-2 word, consumed at t+1: tightest slack) published first
      pub64(pnd + ((size_t)((t + 1) & 3) * 2 + 0) * Hq + J, cw0, (unsigned)(t + 1));
      const float f1  = sigm(r_f + x_f1 + wb_f);
      const float iw1 = sigm(r_i + x_i1 + wb_i);
      const float g1  = tanhf(r_g + x_g1 + wb_g);
      const float cw1 = f1 * c1 + iw1 * g1;
      pub64(pnd + ((size_t)((t + 3) & 3) * 2 + 1) * Hq + J, cw1, (unsigned)(t + 1));
    }
    // no barrier here: next A1 touches only shH[par^1]/shx[par^1] (disjoint),
    // next A2 LDS writes are fenced by S1; pend LDS buffers re-written only
    // after S2 of this step (cross-thread ordering via S1/S2 chain).
  }
}

extern "C" void kernel_launch(void* const* d_in, const int* in_sizes, int n_in,
                              void* d_out, int out_size, void* d_ws, size_t ws_size,
                              hipStream_t stream){
  const float* char_emb = (const float*)d_in[0];
  const int*   word_ids = (const int*)d_in[1];
  const float* sense    = (const float*)d_in[2];
  const float* w_ih     = (const float*)d_in[3];
  const float* w_hh     = (const float*)d_in[4];
  const float* bb       = (const float*)d_in[5];
  const float* aw_ih    = (const float*)d_in[6];
  const float* aw_hh    = (const float*)d_in[7];
  const float* ab       = (const float*)d_in[8];
  const float* ww_ih    = (const float*)d_in[9];
  const float* ww_hh    = (const float*)d_in[10];
  const float* wb       = (const float*)d_in[11];
  unsigned char* ws = (unsigned char*)d_ws;
  float* out = (float*)d_out;

  // zero all generation words (h_pub + pend) — ws is re-poisoned before every launch
  hipMemsetAsync(ws, 0, WIHT_OFF, stream);

  // one-time (per launch) weight convert+transpose to bf16
  transpose_bf16<<<512, NTHR, 0, stream>>>(w_ih,  (__hip_bfloat16*)(ws + WIHT_OFF),  7, 128*1536, 1536);
  transpose_bf16<<<512, NTHR, 0, stream>>>(w_hh,  (__hip_bfloat16*)(ws + WHHT_OFF),  9, 512*1536, 1536);
  transpose_bf16<<<512, NTHR, 0, stream>>>(aw_ih, (__hip_bfloat16*)(ws + AWIHT_OFF), 7, 128*512,  512);
  transpose_bf16<<<512, NTHR, 0, stream>>>(aw_hh, (__hip_bfloat16*)(ws + AWHHT_OFF), 9, 512*512,  512);
  transpose_bf16<<<512, NTHR, 0, stream>>>(ww_ih, (__hip_bfloat16*)(ws + WWIHT_OFF), 7, 128*1536, 1536);
  transpose_bf16<<<512, NTHR, 0, stream>>>(ww_hh, (__hip_bfloat16*)(ws + WWHHT_OFF), 9, 512*1536, 1536);

  dim3 grid(Bq, NWG);   // x = seq (XCD-local heuristic), y = wg slice
  lattice_main<<<grid, NTHR, 0, stream>>>(char_emb, word_ids, sense, bb, ab, wb, ws, out);
}